// Round 1
// baseline (725.063 us; speedup 1.0000x reference)
//
#include <hip/hip_runtime.h>

#define N_NODES 50000
#define N_EDGES 640000
#define HIDDEN 128
#define NUM_GRAPHS 50
#define EPS 1e-5f

// ---------------- kernels ----------------

// deg[col[e]] += edge_attr[e]
__global__ void deg_kernel(const int* __restrict__ col, const float* __restrict__ ea,
                           float* __restrict__ deg) {
    int e = blockIdx.x * blockDim.x + threadIdx.x;
    if (e < N_EDGES) atomicAdd(&deg[col[e]], ea[e]);
}

// dinv = deg > 0 ? 1/sqrt(deg) : 0   (in place)
__global__ void dinv_kernel(float* __restrict__ deg) {
    int i = blockIdx.x * blockDim.x + threadIdx.x;
    if (i < N_NODES) {
        float d = deg[i];
        deg[i] = (d > 0.f) ? (1.0f / sqrtf(d)) : 0.f;
    }
}

// one wave (64 lanes) per edge; lane handles channels {lane, lane+64}
__global__ void scatter_kernel(const int* __restrict__ row, const int* __restrict__ col,
                               const float* __restrict__ ea, const float* __restrict__ dinv,
                               const float* __restrict__ node, float* __restrict__ out) {
    int idx = blockIdx.x * blockDim.x + threadIdx.x;
    int e = idx >> 6;
    int lane = idx & 63;
    if (e >= N_EDGES) return;
    int r = row[e];
    int c = col[e];
    float w = dinv[r] * ea[e] * dinv[c];
    const float* src = node + (size_t)r * HIDDEN;
    float* dst = out + (size_t)c * HIDDEN;
    atomicAdd(&dst[lane], src[lane] * w);
    atomicAdd(&dst[lane + 64], src[lane + 64] * w);
}

// per-(graph,channel) sum and sumsq of h; 128 threads/block (one per channel),
// each block covers a chunk of 64 nodes; batch_ptr is sorted -> run-length flush
__global__ void stats_kernel(const float* __restrict__ h, const int* __restrict__ batch,
                             float* __restrict__ sum, float* __restrict__ sumsq) {
    int c = threadIdx.x;  // 0..127
    int i0 = blockIdx.x * 64;
    int i1 = i0 + 64;
    if (i1 > N_NODES) i1 = N_NODES;
    int gcur = -1;
    float s = 0.f, ss = 0.f;
    for (int i = i0; i < i1; ++i) {
        int g = batch[i];
        if (g != gcur) {
            if (gcur >= 0) {
                atomicAdd(&sum[gcur * HIDDEN + c], s);
                atomicAdd(&sumsq[gcur * HIDDEN + c], ss);
            }
            gcur = g; s = 0.f; ss = 0.f;
        }
        float v = h[(size_t)i * HIDDEN + c];
        s += v;
        ss += v * v;
    }
    if (gcur >= 0) {
        atomicAdd(&sum[gcur * HIDDEN + c], s);
        atomicAdd(&sumsq[gcur * HIDDEN + c], ss);
    }
}

__global__ void cnt_kernel(const int* __restrict__ batch, float* __restrict__ cnt) {
    int i = blockIdx.x * blockDim.x + threadIdx.x;
    if (i < N_NODES) atomicAdd(&cnt[batch[i]], 1.0f);
}

// per-(g,c): msc = mean*mean_scale[c]; scale = weight[c]/sqrt(var+eps)
__global__ void finalize_kernel(const float* __restrict__ sum, const float* __restrict__ sumsq,
                                const float* __restrict__ cnt,
                                const float* __restrict__ mean_scale,
                                const float* __restrict__ weight,
                                float* __restrict__ msc, float* __restrict__ scale) {
    int t = blockIdx.x * blockDim.x + threadIdx.x;
    if (t >= NUM_GRAPHS * HIDDEN) return;
    int g = t / HIDDEN;
    int c = t - g * HIDDEN;
    float n = fmaxf(cnt[g], 1.0f);
    float mean = sum[t] / n;
    float m2 = sumsq[t] / n;
    float ms = mean * mean_scale[c];
    float var = m2 - 2.f * ms * mean + ms * ms;
    msc[t] = ms;
    scale[t] = weight[c] / sqrtf(var + EPS);
}

// out = relu((h - msc)*scale + bias), float4-vectorized, in place on d_out
__global__ void norm_kernel(float* __restrict__ out, const int* __restrict__ batch,
                            const float* __restrict__ msc, const float* __restrict__ scale,
                            const float* __restrict__ bias) {
    int t = blockIdx.x * blockDim.x + threadIdx.x;  // one float4 per thread
    if (t >= N_NODES * HIDDEN / 4) return;
    int node_i = t >> 5;          // 32 float4 per node
    int c4 = (t & 31) << 2;
    int g = batch[node_i];
    float4 h = ((const float4*)out)[t];
    float4 m = *(const float4*)&msc[g * HIDDEN + c4];
    float4 sc = *(const float4*)&scale[g * HIDDEN + c4];
    float4 b = *(const float4*)&bias[c4];
    float4 o;
    o.x = fmaxf((h.x - m.x) * sc.x + b.x, 0.f);
    o.y = fmaxf((h.y - m.y) * sc.y + b.y, 0.f);
    o.z = fmaxf((h.z - m.z) * sc.z + b.z, 0.f);
    o.w = fmaxf((h.w - m.w) * sc.w + b.w, 0.f);
    ((float4*)out)[t] = o;
}

// ---------------- launch ----------------

extern "C" void kernel_launch(void* const* d_in, const int* in_sizes, int n_in,
                              void* d_out, int out_size, void* d_ws, size_t ws_size,
                              hipStream_t stream) {
    const float* node       = (const float*)d_in[0];
    const int*   eidx       = (const int*)d_in[1];   // [2, E] flat
    const float* ea         = (const float*)d_in[2];
    const int*   batch      = (const int*)d_in[3];
    const float* weight     = (const float*)d_in[4];
    const float* bias       = (const float*)d_in[5];
    const float* mean_scale = (const float*)d_in[6];
    float* out = (float*)d_out;

    const int* row = eidx;
    const int* col = eidx + N_EDGES;

    // ws layout (floats)
    float* ws    = (float*)d_ws;
    float* deg   = ws;                 // N (becomes dinv in place)
    float* sum   = ws + 50048;         // 6400
    float* sumsq = sum + 6400;         // 6400
    float* cnt   = sumsq + 6400;       // 64 (50 used)
    float* msc   = cnt + 64;           // 6400
    float* scale = msc + 6400;         // 6400

    // zero the accumulator regions: deg + sum + sumsq + cnt
    size_t zero_floats = 50048 + 6400 + 6400 + 64;
    hipMemsetAsync(d_ws, 0, zero_floats * sizeof(float), stream);

    // residual base: out = node
    hipMemcpyAsync(d_out, node, (size_t)N_NODES * HIDDEN * sizeof(float),
                   hipMemcpyDeviceToDevice, stream);

    deg_kernel<<<(N_EDGES + 255) / 256, 256, 0, stream>>>(col, ea, deg);
    dinv_kernel<<<(N_NODES + 255) / 256, 256, 0, stream>>>(deg);

    long long scatter_threads = (long long)N_EDGES * 64;
    scatter_kernel<<<(int)((scatter_threads + 255) / 256), 256, 0, stream>>>(
        row, col, ea, deg, node, out);

    stats_kernel<<<(N_NODES + 63) / 64, 128, 0, stream>>>(out, batch, sum, sumsq);
    cnt_kernel<<<(N_NODES + 255) / 256, 256, 0, stream>>>(batch, cnt);

    finalize_kernel<<<(NUM_GRAPHS * HIDDEN + 255) / 256, 256, 0, stream>>>(
        sum, sumsq, cnt, mean_scale, weight, msc, scale);

    norm_kernel<<<(N_NODES * HIDDEN / 4 + 255) / 256, 256, 0, stream>>>(
        out, batch, msc, scale, bias);
}

// Round 2
// 435.123 us; speedup vs baseline: 1.6663x; 1.6663x over previous
//
#include <hip/hip_runtime.h>

#define N_NODES 50000
#define N_EDGES 640000
#define HIDDEN 128
#define NUM_GRAPHS 50
#define EPS 1e-5f

// ---------------- kernels ----------------

// deg[col[e]] += edge_attr[e]
__global__ void deg_kernel(const int* __restrict__ col, const float* __restrict__ ea,
                           float* __restrict__ deg) {
    int e = blockIdx.x * blockDim.x + threadIdx.x;
    if (e < N_EDGES) atomicAdd(&deg[col[e]], ea[e]);
}

// dinv = deg > 0 ? 1/sqrt(deg) : 0   (in place)
__global__ void dinv_kernel(float* __restrict__ deg) {
    int i = blockIdx.x * blockDim.x + threadIdx.x;
    if (i < N_NODES) {
        float d = deg[i];
        deg[i] = (d > 0.f) ? (1.0f / sqrtf(d)) : 0.f;
    }
}

// one wave (64 lanes) per edge; lane handles channels {lane, lane+64}
__global__ void scatter_kernel(const int* __restrict__ row, const int* __restrict__ col,
                               const float* __restrict__ ea, const float* __restrict__ dinv,
                               const float* __restrict__ node, float* __restrict__ out) {
    int idx = blockIdx.x * blockDim.x + threadIdx.x;
    int e = idx >> 6;
    int lane = idx & 63;
    if (e >= N_EDGES) return;
    int r = row[e];
    int c = col[e];
    float w = dinv[r] * ea[e] * dinv[c];
    const float* src = node + (size_t)r * HIDDEN;
    float* dst = out + (size_t)c * HIDDEN;
    atomicAdd(&dst[lane], src[lane] * w);
    atomicAdd(&dst[lane + 64], src[lane + 64] * w);
}

// per-(graph,channel) sum and sumsq of h; 128 threads/block (one per channel),
// each block covers a chunk of 64 nodes; batch_ptr is sorted -> run-length flush
__global__ void stats_kernel(const float* __restrict__ h, const int* __restrict__ batch,
                             float* __restrict__ sum, float* __restrict__ sumsq) {
    int c = threadIdx.x;  // 0..127
    int i0 = blockIdx.x * 64;
    int i1 = i0 + 64;
    if (i1 > N_NODES) i1 = N_NODES;
    int gcur = -1;
    float s = 0.f, ss = 0.f;
    for (int i = i0; i < i1; ++i) {
        int g = batch[i];
        if (g != gcur) {
            if (gcur >= 0) {
                atomicAdd(&sum[gcur * HIDDEN + c], s);
                atomicAdd(&sumsq[gcur * HIDDEN + c], ss);
            }
            gcur = g; s = 0.f; ss = 0.f;
        }
        float v = h[(size_t)i * HIDDEN + c];
        s += v;
        ss += v * v;
    }
    if (gcur >= 0) {
        atomicAdd(&sum[gcur * HIDDEN + c], s);
        atomicAdd(&sumsq[gcur * HIDDEN + c], ss);
    }
}

// batch_ptr sorted -> counts via binary search; one thread per graph
__global__ void cnt_bs_kernel(const int* __restrict__ batch, float* __restrict__ cnt) {
    int g = threadIdx.x;
    if (g >= NUM_GRAPHS) return;
    int lo0 = 0, hi0 = N_NODES;        // lower_bound(g)
    while (lo0 < hi0) { int mid = (lo0 + hi0) >> 1; if (batch[mid] < g) lo0 = mid + 1; else hi0 = mid; }
    int lo1 = lo0, hi1 = N_NODES;      // lower_bound(g+1)
    while (lo1 < hi1) { int mid = (lo1 + hi1) >> 1; if (batch[mid] < g + 1) lo1 = mid + 1; else hi1 = mid; }
    cnt[g] = (float)(lo1 - lo0);
}

// per-(g,c): msc = mean*mean_scale[c]; scale = weight[c]/sqrt(var+eps)
__global__ void finalize_kernel(const float* __restrict__ sum, const float* __restrict__ sumsq,
                                const float* __restrict__ cnt,
                                const float* __restrict__ mean_scale,
                                const float* __restrict__ weight,
                                float* __restrict__ msc, float* __restrict__ scale) {
    int t = blockIdx.x * blockDim.x + threadIdx.x;
    if (t >= NUM_GRAPHS * HIDDEN) return;
    int g = t / HIDDEN;
    int c = t - g * HIDDEN;
    float n = fmaxf(cnt[g], 1.0f);
    float mean = sum[t] / n;
    float m2 = sumsq[t] / n;
    float ms = mean * mean_scale[c];
    float var = m2 - 2.f * ms * mean + ms * ms;
    msc[t] = ms;
    scale[t] = weight[c] / sqrtf(var + EPS);
}

// out = relu((h - msc)*scale + bias), float4-vectorized, in place on d_out
__global__ void norm_kernel(float* __restrict__ out, const int* __restrict__ batch,
                            const float* __restrict__ msc, const float* __restrict__ scale,
                            const float* __restrict__ bias) {
    int t = blockIdx.x * blockDim.x + threadIdx.x;  // one float4 per thread
    if (t >= N_NODES * HIDDEN / 4) return;
    int node_i = t >> 5;          // 32 float4 per node
    int c4 = (t & 31) << 2;
    int g = batch[node_i];
    float4 h = ((const float4*)out)[t];
    float4 m = *(const float4*)&msc[g * HIDDEN + c4];
    float4 sc = *(const float4*)&scale[g * HIDDEN + c4];
    float4 b = *(const float4*)&bias[c4];
    float4 o;
    o.x = fmaxf((h.x - m.x) * sc.x + b.x, 0.f);
    o.y = fmaxf((h.y - m.y) * sc.y + b.y, 0.f);
    o.z = fmaxf((h.z - m.z) * sc.z + b.z, 0.f);
    o.w = fmaxf((h.w - m.w) * sc.w + b.w, 0.f);
    ((float4*)out)[t] = o;
}

// ---------------- launch ----------------

extern "C" void kernel_launch(void* const* d_in, const int* in_sizes, int n_in,
                              void* d_out, int out_size, void* d_ws, size_t ws_size,
                              hipStream_t stream) {
    const float* node       = (const float*)d_in[0];
    const int*   eidx       = (const int*)d_in[1];   // [2, E] flat
    const float* ea         = (const float*)d_in[2];
    const int*   batch      = (const int*)d_in[3];
    const float* weight     = (const float*)d_in[4];
    const float* bias       = (const float*)d_in[5];
    const float* mean_scale = (const float*)d_in[6];
    float* out = (float*)d_out;

    const int* row = eidx;
    const int* col = eidx + N_EDGES;

    // ws layout (floats)
    float* ws    = (float*)d_ws;
    float* deg   = ws;                 // N (becomes dinv in place)
    float* sum   = ws + 50048;         // 6400
    float* sumsq = sum + 6400;         // 6400
    float* cnt   = sumsq + 6400;       // 64 (50 used)
    float* msc   = cnt + 64;           // 6400
    float* scale = msc + 6400;         // 6400

    // zero the accumulator regions: deg + sum + sumsq + cnt
    size_t zero_floats = 50048 + 6400 + 6400 + 64;
    hipMemsetAsync(d_ws, 0, zero_floats * sizeof(float), stream);

    // residual base: out = node
    hipMemcpyAsync(d_out, node, (size_t)N_NODES * HIDDEN * sizeof(float),
                   hipMemcpyDeviceToDevice, stream);

    deg_kernel<<<(N_EDGES + 255) / 256, 256, 0, stream>>>(col, ea, deg);
    dinv_kernel<<<(N_NODES + 255) / 256, 256, 0, stream>>>(deg);

    long long scatter_threads = (long long)N_EDGES * 64;
    scatter_kernel<<<(int)((scatter_threads + 255) / 256), 256, 0, stream>>>(
        row, col, ea, deg, node, out);

    stats_kernel<<<(N_NODES + 63) / 64, 128, 0, stream>>>(out, batch, sum, sumsq);
    cnt_bs_kernel<<<1, 64, 0, stream>>>(batch, cnt);

    finalize_kernel<<<(NUM_GRAPHS * HIDDEN + 255) / 256, 256, 0, stream>>>(
        sum, sumsq, cnt, mean_scale, weight, msc, scale);

    norm_kernel<<<(N_NODES * HIDDEN / 4 + 255) / 256, 256, 0, stream>>>(
        out, batch, msc, scale, bias);
}

// Round 3
// 306.655 us; speedup vs baseline: 2.3644x; 1.4189x over previous
//
#include <hip/hip_runtime.h>

#define N_NODES 50000
#define N_EDGES 640000
#define HIDDEN 128
#define NUM_GRAPHS 50
#define EPS 1e-5f
#define NBLK 196  // ceil(N_NODES/256)

// ---------------- shared kernels ----------------

// dinv = deg > 0 ? 1/sqrt(deg) : 0   (in place)
__global__ void dinv_kernel(float* __restrict__ deg) {
    int i = blockIdx.x * blockDim.x + threadIdx.x;
    if (i < N_NODES) {
        float d = deg[i];
        deg[i] = (d > 0.f) ? (1.0f / sqrtf(d)) : 0.f;
    }
}

// per-(graph,channel) sum and sumsq of h
__global__ void stats_kernel(const float* __restrict__ h, const int* __restrict__ batch,
                             float* __restrict__ sum, float* __restrict__ sumsq) {
    int c = threadIdx.x;  // 0..127
    int i0 = blockIdx.x * 64;
    int i1 = i0 + 64;
    if (i1 > N_NODES) i1 = N_NODES;
    int gcur = -1;
    float s = 0.f, ss = 0.f;
    for (int i = i0; i < i1; ++i) {
        int g = batch[i];
        if (g != gcur) {
            if (gcur >= 0) {
                atomicAdd(&sum[gcur * HIDDEN + c], s);
                atomicAdd(&sumsq[gcur * HIDDEN + c], ss);
            }
            gcur = g; s = 0.f; ss = 0.f;
        }
        float v = h[(size_t)i * HIDDEN + c];
        s += v;
        ss += v * v;
    }
    if (gcur >= 0) {
        atomicAdd(&sum[gcur * HIDDEN + c], s);
        atomicAdd(&sumsq[gcur * HIDDEN + c], ss);
    }
}

// batch sorted -> per-graph counts via binary search
__global__ void cnt_bs_kernel(const int* __restrict__ batch, float* __restrict__ cnt) {
    int g = threadIdx.x;
    if (g >= NUM_GRAPHS) return;
    int lo0 = 0, hi0 = N_NODES;
    while (lo0 < hi0) { int mid = (lo0 + hi0) >> 1; if (batch[mid] < g) lo0 = mid + 1; else hi0 = mid; }
    int lo1 = lo0, hi1 = N_NODES;
    while (lo1 < hi1) { int mid = (lo1 + hi1) >> 1; if (batch[mid] < g + 1) lo1 = mid + 1; else hi1 = mid; }
    cnt[g] = (float)(lo1 - lo0);
}

__global__ void finalize_kernel(const float* __restrict__ sum, const float* __restrict__ sumsq,
                                const float* __restrict__ cnt,
                                const float* __restrict__ mean_scale,
                                const float* __restrict__ weight,
                                float* __restrict__ msc, float* __restrict__ scale) {
    int t = blockIdx.x * blockDim.x + threadIdx.x;
    if (t >= NUM_GRAPHS * HIDDEN) return;
    int g = t / HIDDEN;
    int c = t - g * HIDDEN;
    float n = fmaxf(cnt[g], 1.0f);
    float mean = sum[t] / n;
    float m2 = sumsq[t] / n;
    float ms = mean * mean_scale[c];
    float var = m2 - 2.f * ms * mean + ms * ms;
    msc[t] = ms;
    scale[t] = weight[c] / sqrtf(var + EPS);
}

__global__ void norm_kernel(float* __restrict__ out, const int* __restrict__ batch,
                            const float* __restrict__ msc, const float* __restrict__ scale,
                            const float* __restrict__ bias) {
    int t = blockIdx.x * blockDim.x + threadIdx.x;
    if (t >= N_NODES * HIDDEN / 4) return;
    int node_i = t >> 5;
    int c4 = (t & 31) << 2;
    int g = batch[node_i];
    float4 h = ((const float4*)out)[t];
    float4 m = *(const float4*)&msc[g * HIDDEN + c4];
    float4 sc = *(const float4*)&scale[g * HIDDEN + c4];
    float4 b = *(const float4*)&bias[c4];
    float4 o;
    o.x = fmaxf((h.x - m.x) * sc.x + b.x, 0.f);
    o.y = fmaxf((h.y - m.y) * sc.y + b.y, 0.f);
    o.z = fmaxf((h.z - m.z) * sc.z + b.z, 0.f);
    o.w = fmaxf((h.w - m.w) * sc.w + b.w, 0.f);
    ((float4*)out)[t] = o;
}

// ---------------- CSR-gather path ----------------

// cnt[col]++ (int) and deg[col] += ea (float)
__global__ void hist_kernel(const int* __restrict__ col, const float* __restrict__ ea,
                            int* __restrict__ cnt, float* __restrict__ deg) {
    int e = blockIdx.x * blockDim.x + threadIdx.x;
    if (e >= N_EDGES) return;
    int c = col[e];
    atomicAdd(&cnt[c], 1);
    atomicAdd(&deg[c], ea[e]);
}

__global__ void scan1_kernel(const int* __restrict__ cnt, int* __restrict__ bsum) {
    __shared__ int lds[256];
    int i = blockIdx.x * 256 + threadIdx.x;
    lds[threadIdx.x] = (i < N_NODES) ? cnt[i] : 0;
    __syncthreads();
    for (int off = 128; off > 0; off >>= 1) {
        if (threadIdx.x < off) lds[threadIdx.x] += lds[threadIdx.x + off];
        __syncthreads();
    }
    if (threadIdx.x == 0) bsum[blockIdx.x] = lds[0];
}

__global__ void scan2_kernel(const int* __restrict__ bsum, int* __restrict__ boff) {
    __shared__ int lds[256];
    int t = threadIdx.x;
    int v = (t < NBLK) ? bsum[t] : 0;
    lds[t] = v;
    __syncthreads();
    for (int off = 1; off < 256; off <<= 1) {
        int x = (t >= off) ? lds[t - off] : 0;
        __syncthreads();
        lds[t] += x;
        __syncthreads();
    }
    if (t < NBLK) boff[t] = lds[t] - v;  // exclusive
}

__global__ void scan3_kernel(const int* __restrict__ cnt, const int* __restrict__ boff,
                             int* __restrict__ rowptr, int* __restrict__ woff) {
    __shared__ int lds[256];
    int i = blockIdx.x * 256 + threadIdx.x;
    int v = (i < N_NODES) ? cnt[i] : 0;
    lds[threadIdx.x] = v;
    __syncthreads();
    for (int off = 1; off < 256; off <<= 1) {
        int x = (threadIdx.x >= off) ? lds[threadIdx.x - off] : 0;
        __syncthreads();
        lds[threadIdx.x] += x;
        __syncthreads();
    }
    if (i < N_NODES) {
        int ex = boff[blockIdx.x] + lds[threadIdx.x] - v;
        rowptr[i] = ex;
        woff[i] = ex;
    }
}

// scatter edges into CSR slots; store (srcidx, dinv[src]*ea) packed
__global__ void place_kernel(const int* __restrict__ row, const int* __restrict__ col,
                             const float* __restrict__ ea, const float* __restrict__ dinv,
                             int* __restrict__ woff, int2* __restrict__ edat) {
    int e = blockIdx.x * blockDim.x + threadIdx.x;
    if (e >= N_EDGES) return;
    int r = row[e], c = col[e];
    int pos = atomicAdd(&woff[c], 1);
    float w = dinv[r] * ea[e];
    edat[pos] = make_int2(r, __float_as_int(w));
}

// one wave per target node; lane handles float2 of channels; fused residual
__global__ void gather_kernel(const int* __restrict__ rowptr, const int* __restrict__ cnt,
                              const int2* __restrict__ edat, const float* __restrict__ dinv,
                              const float* __restrict__ node, float* __restrict__ out) {
    int n = blockIdx.x * 4 + (threadIdx.x >> 6);
    int lane = threadIdx.x & 63;
    if (n >= N_NODES) return;
    int start = rowptr[n];
    int end = start + cnt[n];
    float dn = dinv[n];
    float2 acc = {0.f, 0.f};
    for (int j = start; j < end; ++j) {
        int2 ed = edat[j];
        float w = __int_as_float(ed.y);
        float2 v = ((const float2*)(node + (size_t)ed.x * HIDDEN))[lane];
        acc.x += v.x * w;
        acc.y += v.y * w;
    }
    float2 base = ((const float2*)(node + (size_t)n * HIDDEN))[lane];
    float2 o = {base.x + dn * acc.x, base.y + dn * acc.y};
    ((float2*)(out + (size_t)n * HIDDEN))[lane] = o;
}

// ---------------- fallback (atomic scatter) ----------------

__global__ void deg_kernel(const int* __restrict__ col, const float* __restrict__ ea,
                           float* __restrict__ deg) {
    int e = blockIdx.x * blockDim.x + threadIdx.x;
    if (e < N_EDGES) atomicAdd(&deg[col[e]], ea[e]);
}

__global__ void scatter_kernel(const int* __restrict__ row, const int* __restrict__ col,
                               const float* __restrict__ ea, const float* __restrict__ dinv,
                               const float* __restrict__ node, float* __restrict__ out) {
    int idx = blockIdx.x * blockDim.x + threadIdx.x;
    int e = idx >> 6;
    int lane = idx & 63;
    if (e >= N_EDGES) return;
    int r = row[e];
    int c = col[e];
    float w = dinv[r] * ea[e] * dinv[c];
    const float* src = node + (size_t)r * HIDDEN;
    float* dst = out + (size_t)c * HIDDEN;
    atomicAdd(&dst[lane], src[lane] * w);
    atomicAdd(&dst[lane + 64], src[lane + 64] * w);
}

// ---------------- launch ----------------

extern "C" void kernel_launch(void* const* d_in, const int* in_sizes, int n_in,
                              void* d_out, int out_size, void* d_ws, size_t ws_size,
                              hipStream_t stream) {
    const float* node       = (const float*)d_in[0];
    const int*   eidx       = (const int*)d_in[1];   // [2, E] flat
    const float* ea         = (const float*)d_in[2];
    const int*   batch      = (const int*)d_in[3];
    const float* weight     = (const float*)d_in[4];
    const float* bias       = (const float*)d_in[5];
    const float* mean_scale = (const float*)d_in[6];
    float* out = (float*)d_out;

    const int* row = eidx;
    const int* col = eidx + N_EDGES;

    // ws layout in 4B units; zeroed regions first
    // [deg 50048][cnt 50048][sum 6400][sumsq 6400]  <- one memset
    // [rowptr 50048][woff 50048][edat 2*640000][gcnt 64][msc 6400][scale 6400][bsum 256][boff 256]
    char* wsb = (char*)d_ws;
    float* deg    = (float*)wsb;
    int*   cnt_i  = (int*)(deg + 50048);
    float* sum    = (float*)(cnt_i + 50048);
    float* sumsq  = sum + 6400;
    int*   rowptr = (int*)(sumsq + 6400);
    int*   woff   = rowptr + 50048;
    int2*  edat   = (int2*)(woff + 50048);
    float* gcnt   = (float*)(edat + N_EDGES);
    float* msc    = gcnt + 64;
    float* scale  = msc + 6400;
    int*   bsum   = (int*)(scale + 6400);
    int*   boff   = bsum + 256;
    size_t need = (size_t)((char*)(boff + 256) - wsb);

    if (ws_size >= need) {
        // zero: deg + cnt + sum + sumsq (contiguous)
        hipMemsetAsync(d_ws, 0, (50048 * 2 + 6400 * 2) * sizeof(float), stream);

        hist_kernel<<<(N_EDGES + 255) / 256, 256, 0, stream>>>(col, ea, cnt_i, deg);
        dinv_kernel<<<(N_NODES + 255) / 256, 256, 0, stream>>>(deg);
        scan1_kernel<<<NBLK, 256, 0, stream>>>(cnt_i, bsum);
        scan2_kernel<<<1, 256, 0, stream>>>(bsum, boff);
        scan3_kernel<<<NBLK, 256, 0, stream>>>(cnt_i, boff, rowptr, woff);
        place_kernel<<<(N_EDGES + 255) / 256, 256, 0, stream>>>(row, col, ea, deg, woff, edat);
        gather_kernel<<<(N_NODES + 3) / 4, 256, 0, stream>>>(rowptr, cnt_i, edat, deg, node, out);
    } else {
        // fallback: atomic scatter path (small ws)
        float* f_sum   = deg + 50048;
        float* f_sumsq = f_sum + 6400;
        float* f_gcnt  = f_sumsq + 6400;
        float* f_msc   = f_gcnt + 64;
        float* f_scale = f_msc + 6400;
        sum = f_sum; sumsq = f_sumsq; gcnt = f_gcnt; msc = f_msc; scale = f_scale;

        hipMemsetAsync(d_ws, 0, (50048 + 6400 * 2 + 64) * sizeof(float), stream);
        hipMemcpyAsync(d_out, node, (size_t)N_NODES * HIDDEN * sizeof(float),
                       hipMemcpyDeviceToDevice, stream);
        deg_kernel<<<(N_EDGES + 255) / 256, 256, 0, stream>>>(col, ea, deg);
        dinv_kernel<<<(N_NODES + 255) / 256, 256, 0, stream>>>(deg);
        long long st = (long long)N_EDGES * 64;
        scatter_kernel<<<(int)((st + 255) / 256), 256, 0, stream>>>(row, col, ea, deg, node, out);
    }

    stats_kernel<<<(N_NODES + 63) / 64, 128, 0, stream>>>(out, batch, sum, sumsq);
    cnt_bs_kernel<<<1, 64, 0, stream>>>(batch, gcnt);
    finalize_kernel<<<(NUM_GRAPHS * HIDDEN + 255) / 256, 256, 0, stream>>>(
        sum, sumsq, gcnt, mean_scale, weight, msc, scale);
    norm_kernel<<<(N_NODES * HIDDEN / 4 + 255) / 256, 256, 0, stream>>>(
        out, batch, msc, scale, bias);
}

// Round 4
// 304.295 us; speedup vs baseline: 2.3828x; 1.0078x over previous
//
#include <hip/hip_runtime.h>

#define N_NODES 50000
#define N_EDGES 640000
#define HIDDEN 128
#define NUM_GRAPHS 50
#define EPS 1e-5f
#define NBLK 196  // ceil(N_NODES/256)

// ---------------- CSR build ----------------

// cnt[col]++ (int) and deg[col] += ea (float)
__global__ void hist_kernel(const int* __restrict__ col, const float* __restrict__ ea,
                            int* __restrict__ cnt, float* __restrict__ deg) {
    int e = blockIdx.x * blockDim.x + threadIdx.x;
    if (e >= N_EDGES) return;
    int c = col[e];
    atomicAdd(&cnt[c], 1);
    atomicAdd(&deg[c], ea[e]);
}

// per-256-block sums of cnt; fused: deg -> dinv in place
__global__ void scan1_kernel(const int* __restrict__ cnt, int* __restrict__ bsum,
                             float* __restrict__ deg) {
    __shared__ int lds[256];
    int i = blockIdx.x * 256 + threadIdx.x;
    if (i < N_NODES) {
        float d = deg[i];
        deg[i] = (d > 0.f) ? (1.0f / sqrtf(d)) : 0.f;
    }
    lds[threadIdx.x] = (i < N_NODES) ? cnt[i] : 0;
    __syncthreads();
    for (int off = 128; off > 0; off >>= 1) {
        if (threadIdx.x < off) lds[threadIdx.x] += lds[threadIdx.x + off];
        __syncthreads();
    }
    if (threadIdx.x == 0) bsum[blockIdx.x] = lds[0];
}

__global__ void scan2_kernel(const int* __restrict__ bsum, int* __restrict__ boff) {
    __shared__ int lds[256];
    int t = threadIdx.x;
    int v = (t < NBLK) ? bsum[t] : 0;
    lds[t] = v;
    __syncthreads();
    for (int off = 1; off < 256; off <<= 1) {
        int x = (t >= off) ? lds[t - off] : 0;
        __syncthreads();
        lds[t] += x;
        __syncthreads();
    }
    if (t < NBLK) boff[t] = lds[t] - v;  // exclusive
}

__global__ void scan3_kernel(const int* __restrict__ cnt, const int* __restrict__ boff,
                             int* __restrict__ rowptr, int* __restrict__ woff) {
    __shared__ int lds[256];
    int i = blockIdx.x * 256 + threadIdx.x;
    int v = (i < N_NODES) ? cnt[i] : 0;
    lds[threadIdx.x] = v;
    __syncthreads();
    for (int off = 1; off < 256; off <<= 1) {
        int x = (threadIdx.x >= off) ? lds[threadIdx.x - off] : 0;
        __syncthreads();
        lds[threadIdx.x] += x;
        __syncthreads();
    }
    if (i < N_NODES) {
        int ex = boff[blockIdx.x] + lds[threadIdx.x] - v;
        rowptr[i] = ex;
        woff[i] = ex;
    }
}

// scatter edges into CSR slots; store (srcidx, dinv[src]*ea) packed
__global__ void place_kernel(const int* __restrict__ row, const int* __restrict__ col,
                             const float* __restrict__ ea, const float* __restrict__ dinv,
                             int* __restrict__ woff, int2* __restrict__ edat) {
    int e = blockIdx.x * blockDim.x + threadIdx.x;
    if (e >= N_EDGES) return;
    int r = row[e], c = col[e];
    int pos = atomicAdd(&woff[c], 1);
    float w = dinv[r] * ea[e];
    edat[pos] = make_int2(r, __float_as_int(w));
}

// one wave per target node; lane = 2 channels; 4-way unrolled for MLP; fused residual
__global__ void gather_kernel(const int* __restrict__ rowptr, const int* __restrict__ cnt,
                              const int2* __restrict__ edat, const float* __restrict__ dinv,
                              const float* __restrict__ node, float* __restrict__ out) {
    int n = blockIdx.x * 4 + (threadIdx.x >> 6);
    int lane = threadIdx.x & 63;
    if (n >= N_NODES) return;
    int j = rowptr[n];
    int end = j + cnt[n];
    float dn = dinv[n];
    float2 a0 = {0.f, 0.f}, a1 = {0.f, 0.f}, a2 = {0.f, 0.f}, a3 = {0.f, 0.f};
    for (; j + 4 <= end; j += 4) {
        int2 e0 = edat[j + 0];
        int2 e1 = edat[j + 1];
        int2 e2 = edat[j + 2];
        int2 e3 = edat[j + 3];
        float2 v0 = ((const float2*)(node + (size_t)e0.x * HIDDEN))[lane];
        float2 v1 = ((const float2*)(node + (size_t)e1.x * HIDDEN))[lane];
        float2 v2 = ((const float2*)(node + (size_t)e2.x * HIDDEN))[lane];
        float2 v3 = ((const float2*)(node + (size_t)e3.x * HIDDEN))[lane];
        float w0 = __int_as_float(e0.y), w1 = __int_as_float(e1.y);
        float w2 = __int_as_float(e2.y), w3 = __int_as_float(e3.y);
        a0.x = fmaf(v0.x, w0, a0.x); a0.y = fmaf(v0.y, w0, a0.y);
        a1.x = fmaf(v1.x, w1, a1.x); a1.y = fmaf(v1.y, w1, a1.y);
        a2.x = fmaf(v2.x, w2, a2.x); a2.y = fmaf(v2.y, w2, a2.y);
        a3.x = fmaf(v3.x, w3, a3.x); a3.y = fmaf(v3.y, w3, a3.y);
    }
    for (; j < end; ++j) {
        int2 e = edat[j];
        float w = __int_as_float(e.y);
        float2 v = ((const float2*)(node + (size_t)e.x * HIDDEN))[lane];
        a0.x = fmaf(v.x, w, a0.x); a0.y = fmaf(v.y, w, a0.y);
    }
    float2 base = ((const float2*)(node + (size_t)n * HIDDEN))[lane];
    float sx = base.x + dn * ((a0.x + a1.x) + (a2.x + a3.x));
    float sy = base.y + dn * ((a0.y + a1.y) + (a2.y + a3.y));
    ((float2*)(out + (size_t)n * HIDDEN))[lane] = make_float2(sx, sy);
}

// ---------------- GraphNorm ----------------

// 256 threads/block: sub-row = tid>>5 (8 rows in flight), c4 = (tid&31)*4
// block covers 64 consecutive nodes; per-thread run-length flush (g monotonic on strided walk)
__global__ void stats_kernel(const float* __restrict__ h, const int* __restrict__ batch,
                             float* __restrict__ sum, float* __restrict__ sumsq) {
    int sub = threadIdx.x >> 5;
    int c4 = (threadIdx.x & 31) << 2;
    int i0 = blockIdx.x * 64;
    float4 s = make_float4(0.f, 0.f, 0.f, 0.f);
    float4 ss = make_float4(0.f, 0.f, 0.f, 0.f);
    int gcur = -1;
    for (int k = 0; k < 8; ++k) {
        int i = i0 + k * 8 + sub;
        if (i >= N_NODES) break;
        int g = batch[i];
        if (g != gcur) {
            if (gcur >= 0) {
                float* sp = &sum[gcur * HIDDEN + c4];
                atomicAdd(sp + 0, s.x); atomicAdd(sp + 1, s.y);
                atomicAdd(sp + 2, s.z); atomicAdd(sp + 3, s.w);
                float* qp = &sumsq[gcur * HIDDEN + c4];
                atomicAdd(qp + 0, ss.x); atomicAdd(qp + 1, ss.y);
                atomicAdd(qp + 2, ss.z); atomicAdd(qp + 3, ss.w);
            }
            gcur = g;
            s = make_float4(0.f, 0.f, 0.f, 0.f);
            ss = make_float4(0.f, 0.f, 0.f, 0.f);
        }
        float4 v = *(const float4*)(h + (size_t)i * HIDDEN + c4);
        s.x += v.x; s.y += v.y; s.z += v.z; s.w += v.w;
        ss.x += v.x * v.x; ss.y += v.y * v.y; ss.z += v.z * v.z; ss.w += v.w * v.w;
    }
    if (gcur >= 0) {
        float* sp = &sum[gcur * HIDDEN + c4];
        atomicAdd(sp + 0, s.x); atomicAdd(sp + 1, s.y);
        atomicAdd(sp + 2, s.z); atomicAdd(sp + 3, s.w);
        float* qp = &sumsq[gcur * HIDDEN + c4];
        atomicAdd(qp + 0, ss.x); atomicAdd(qp + 1, ss.y);
        atomicAdd(qp + 2, ss.z); atomicAdd(qp + 3, ss.w);
    }
}

// per-(g,c): counts via binary search (batch sorted); msc & scale
__global__ void finalize_kernel(const float* __restrict__ sum, const float* __restrict__ sumsq,
                                const int* __restrict__ batch,
                                const float* __restrict__ mean_scale,
                                const float* __restrict__ weight,
                                float* __restrict__ msc, float* __restrict__ scale) {
    int t = blockIdx.x * blockDim.x + threadIdx.x;
    if (t >= NUM_GRAPHS * HIDDEN) return;
    int g = t >> 7;
    int c = t & 127;
    int lo0 = 0, hi0 = N_NODES;
    while (lo0 < hi0) { int m = (lo0 + hi0) >> 1; if (batch[m] < g) lo0 = m + 1; else hi0 = m; }
    int lo1 = lo0, hi1 = N_NODES;
    while (lo1 < hi1) { int m = (lo1 + hi1) >> 1; if (batch[m] < g + 1) lo1 = m + 1; else hi1 = m; }
    float n = fmaxf((float)(lo1 - lo0), 1.0f);
    float mean = sum[t] / n;
    float m2 = sumsq[t] / n;
    float ms = mean * mean_scale[c];
    float var = m2 - 2.f * ms * mean + ms * ms;
    msc[t] = ms;
    scale[t] = weight[c] / sqrtf(var + EPS);
}

__global__ void norm_kernel(float* __restrict__ out, const int* __restrict__ batch,
                            const float* __restrict__ msc, const float* __restrict__ scale,
                            const float* __restrict__ bias) {
    int t = blockIdx.x * blockDim.x + threadIdx.x;
    if (t >= N_NODES * HIDDEN / 4) return;
    int node_i = t >> 5;
    int c4 = (t & 31) << 2;
    int g = batch[node_i];
    float4 h = ((const float4*)out)[t];
    float4 m = *(const float4*)&msc[g * HIDDEN + c4];
    float4 sc = *(const float4*)&scale[g * HIDDEN + c4];
    float4 b = *(const float4*)&bias[c4];
    float4 o;
    o.x = fmaxf((h.x - m.x) * sc.x + b.x, 0.f);
    o.y = fmaxf((h.y - m.y) * sc.y + b.y, 0.f);
    o.z = fmaxf((h.z - m.z) * sc.z + b.z, 0.f);
    o.w = fmaxf((h.w - m.w) * sc.w + b.w, 0.f);
    ((float4*)out)[t] = o;
}

// ---------------- fallback (atomic scatter, small ws) ----------------

__global__ void deg_kernel(const int* __restrict__ col, const float* __restrict__ ea,
                           float* __restrict__ deg) {
    int e = blockIdx.x * blockDim.x + threadIdx.x;
    if (e < N_EDGES) atomicAdd(&deg[col[e]], ea[e]);
}

__global__ void dinv_kernel(float* __restrict__ deg) {
    int i = blockIdx.x * blockDim.x + threadIdx.x;
    if (i < N_NODES) {
        float d = deg[i];
        deg[i] = (d > 0.f) ? (1.0f / sqrtf(d)) : 0.f;
    }
}

__global__ void scatter_kernel(const int* __restrict__ row, const int* __restrict__ col,
                               const float* __restrict__ ea, const float* __restrict__ dinv,
                               const float* __restrict__ node, float* __restrict__ out) {
    int idx = blockIdx.x * blockDim.x + threadIdx.x;
    int e = idx >> 6;
    int lane = idx & 63;
    if (e >= N_EDGES) return;
    int r = row[e];
    int c = col[e];
    float w = dinv[r] * ea[e] * dinv[c];
    const float* src = node + (size_t)r * HIDDEN;
    float* dst = out + (size_t)c * HIDDEN;
    atomicAdd(&dst[lane], src[lane] * w);
    atomicAdd(&dst[lane + 64], src[lane + 64] * w);
}

// ---------------- launch ----------------

extern "C" void kernel_launch(void* const* d_in, const int* in_sizes, int n_in,
                              void* d_out, int out_size, void* d_ws, size_t ws_size,
                              hipStream_t stream) {
    const float* node       = (const float*)d_in[0];
    const int*   eidx       = (const int*)d_in[1];   // [2, E] flat
    const float* ea         = (const float*)d_in[2];
    const int*   batch      = (const int*)d_in[3];
    const float* weight     = (const float*)d_in[4];
    const float* bias       = (const float*)d_in[5];
    const float* mean_scale = (const float*)d_in[6];
    float* out = (float*)d_out;

    const int* row = eidx;
    const int* col = eidx + N_EDGES;

    // ws layout (4B units): zeroed prefix [deg 50048][cnt 50048][sum 6400][sumsq 6400]
    char* wsb = (char*)d_ws;
    float* deg    = (float*)wsb;
    int*   cnt_i  = (int*)(deg + 50048);
    float* sum    = (float*)(cnt_i + 50048);
    float* sumsq  = sum + 6400;
    int*   rowptr = (int*)(sumsq + 6400);
    int*   woff   = rowptr + 50048;
    int2*  edat   = (int2*)(woff + 50048);
    float* msc    = (float*)(edat + N_EDGES);
    float* scale  = msc + 6400;
    int*   bsum   = (int*)(scale + 6400);
    int*   boff   = bsum + 256;
    size_t need = (size_t)((char*)(boff + 256) - wsb);

    if (ws_size >= need) {
        hipMemsetAsync(d_ws, 0, (50048 * 2 + 6400 * 2) * sizeof(float), stream);

        hist_kernel<<<(N_EDGES + 255) / 256, 256, 0, stream>>>(col, ea, cnt_i, deg);
        scan1_kernel<<<NBLK, 256, 0, stream>>>(cnt_i, bsum, deg);  // + dinv fused
        scan2_kernel<<<1, 256, 0, stream>>>(bsum, boff);
        scan3_kernel<<<NBLK, 256, 0, stream>>>(cnt_i, boff, rowptr, woff);
        place_kernel<<<(N_EDGES + 255) / 256, 256, 0, stream>>>(row, col, ea, deg, woff, edat);
        gather_kernel<<<(N_NODES + 3) / 4, 256, 0, stream>>>(rowptr, cnt_i, edat, deg, node, out);
    } else {
        // fallback: atomic scatter path
        float* f_sum   = deg + 50048;
        float* f_sumsq = f_sum + 6400;
        float* f_msc   = f_sumsq + 6400;
        float* f_scale = f_msc + 6400;
        sum = f_sum; sumsq = f_sumsq; msc = f_msc; scale = f_scale;

        hipMemsetAsync(d_ws, 0, (50048 + 6400 * 2) * sizeof(float), stream);
        hipMemcpyAsync(d_out, node, (size_t)N_NODES * HIDDEN * sizeof(float),
                       hipMemcpyDeviceToDevice, stream);
        deg_kernel<<<(N_EDGES + 255) / 256, 256, 0, stream>>>(col, ea, deg);
        dinv_kernel<<<(N_NODES + 255) / 256, 256, 0, stream>>>(deg);
        long long st = (long long)N_EDGES * 64;
        scatter_kernel<<<(int)((st + 255) / 256), 256, 0, stream>>>(row, col, ea, deg, node, out);
    }

    stats_kernel<<<(N_NODES + 63) / 64, 256, 0, stream>>>(out, batch, sum, sumsq);
    finalize_kernel<<<(NUM_GRAPHS * HIDDEN + 255) / 256, 256, 0, stream>>>(
        sum, sumsq, batch, mean_scale, weight, msc, scale);
    norm_kernel<<<(N_NODES * HIDDEN / 4 + 255) / 256, 256, 0, stream>>>(
        out, batch, msc, scale, bias);
}

// Round 6
// 255.671 us; speedup vs baseline: 2.8359x; 1.1902x over previous
//
#include <hip/hip_runtime.h>

#define N_NODES 50000
#define N_EDGES 640000
#define HIDDEN 128
#define NUM_GRAPHS 50
#define EPS 1e-5f
#define NBLK 196  // ceil(N_NODES/256)

#define CNT_SHIFT 44
#define FIX_MASK ((1ULL << CNT_SHIFT) - 1)
#define FIX_SCALE 4294967296.0f   // 2^32
#define FIX_INV (1.0f / 4294967296.0f)

// ---------------- CSR build ----------------

// ONE packed u64 atomic per edge: [63:44]=count, [43:0]=fixed-point sum(ea).
// Return value's count field = this edge's CSR slot rank.
__global__ void hist_kernel(const int* __restrict__ col, const float* __restrict__ ea,
                            unsigned long long* __restrict__ cnt64, int* __restrict__ rank) {
    int e = blockIdx.x * blockDim.x + threadIdx.x;
    if (e >= N_EDGES) return;
    int c = col[e];
    unsigned long long fx = (unsigned long long)(ea[e] * FIX_SCALE + 0.5f);
    unsigned long long old = atomicAdd(&cnt64[c], (1ULL << CNT_SHIFT) | fx);
    rank[e] = (int)(old >> CNT_SHIFT);
}

// unpack cnt64 -> dinv; per-256-block sums of cnt
__global__ void scan1_kernel(const unsigned long long* __restrict__ cnt64,
                             int* __restrict__ bsum, float* __restrict__ dinv) {
    __shared__ int lds[256];
    int i = blockIdx.x * 256 + threadIdx.x;
    int c = 0;
    if (i < N_NODES) {
        unsigned long long v = cnt64[i];
        c = (int)(v >> CNT_SHIFT);
        unsigned long long lo = v & FIX_MASK;
        float deg = (float)lo * FIX_INV;
        dinv[i] = (lo != 0ULL) ? (1.0f / sqrtf(deg)) : 0.f;
    }
    lds[threadIdx.x] = c;
    __syncthreads();
    for (int off = 128; off > 0; off >>= 1) {
        if (threadIdx.x < off) lds[threadIdx.x] += lds[threadIdx.x + off];
        __syncthreads();
    }
    if (threadIdx.x == 0) bsum[blockIdx.x] = lds[0];
}

__global__ void scan2_kernel(const int* __restrict__ bsum, int* __restrict__ boff) {
    __shared__ int lds[256];
    int t = threadIdx.x;
    int v = (t < NBLK) ? bsum[t] : 0;
    lds[t] = v;
    __syncthreads();
    for (int off = 1; off < 256; off <<= 1) {
        int x = (t >= off) ? lds[t - off] : 0;
        __syncthreads();
        lds[t] += x;
        __syncthreads();
    }
    if (t < NBLK) boff[t] = lds[t] - v;  // exclusive
}

__global__ void scan3_kernel(const unsigned long long* __restrict__ cnt64,
                             const int* __restrict__ boff, int* __restrict__ rowptr) {
    __shared__ int lds[256];
    int i = blockIdx.x * 256 + threadIdx.x;
    int v = (i < N_NODES) ? (int)(cnt64[i] >> CNT_SHIFT) : 0;
    lds[threadIdx.x] = v;
    __syncthreads();
    for (int off = 1; off < 256; off <<= 1) {
        int x = (threadIdx.x >= off) ? lds[threadIdx.x - off] : 0;
        __syncthreads();
        lds[threadIdx.x] += x;
        __syncthreads();
    }
    if (i < N_NODES) rowptr[i] = boff[blockIdx.x] + lds[threadIdx.x] - v;  // exclusive
}

// atomic-free placement: slot = rowptr[col] + rank[e]
__global__ void place_kernel(const int* __restrict__ row, const int* __restrict__ col,
                             const float* __restrict__ ea, const float* __restrict__ rank,
                             const int* __restrict__ rowptr, const float* __restrict__ dinv,
                             int2* __restrict__ edat) {
    int e = blockIdx.x * blockDim.x + threadIdx.x;
    if (e >= N_EDGES) return;
    int r = row[e], c = col[e];
    float w = dinv[r] * ea[e];
    int pos = rowptr[c] + ((const int*)rank)[e];
    edat[pos] = make_int2(r, __float_as_int(w));
}

// one wave per target node; lane = 2 channels; 8-deep edge pipeline; fused residual
__global__ void gather_kernel(const int* __restrict__ rowptr,
                              const unsigned long long* __restrict__ cnt64,
                              const int2* __restrict__ edat, const float* __restrict__ dinv,
                              const float* __restrict__ node, float* __restrict__ out) {
    int n = blockIdx.x * 4 + (threadIdx.x >> 6);
    int lane = threadIdx.x & 63;
    if (n >= N_NODES) return;
    int j = rowptr[n];
    int end = j + (int)(cnt64[n] >> CNT_SHIFT);
    float dn = dinv[n];
    float2 a0 = {0.f, 0.f}, a1 = {0.f, 0.f}, a2 = {0.f, 0.f}, a3 = {0.f, 0.f};
    for (; j + 8 <= end; j += 8) {
        int2 e0 = edat[j + 0]; int2 e1 = edat[j + 1];
        int2 e2 = edat[j + 2]; int2 e3 = edat[j + 3];
        int2 e4 = edat[j + 4]; int2 e5 = edat[j + 5];
        int2 e6 = edat[j + 6]; int2 e7 = edat[j + 7];
        float2 v0 = ((const float2*)(node + (size_t)e0.x * HIDDEN))[lane];
        float2 v1 = ((const float2*)(node + (size_t)e1.x * HIDDEN))[lane];
        float2 v2 = ((const float2*)(node + (size_t)e2.x * HIDDEN))[lane];
        float2 v3 = ((const float2*)(node + (size_t)e3.x * HIDDEN))[lane];
        float2 v4 = ((const float2*)(node + (size_t)e4.x * HIDDEN))[lane];
        float2 v5 = ((const float2*)(node + (size_t)e5.x * HIDDEN))[lane];
        float2 v6 = ((const float2*)(node + (size_t)e6.x * HIDDEN))[lane];
        float2 v7 = ((const float2*)(node + (size_t)e7.x * HIDDEN))[lane];
        float w0 = __int_as_float(e0.y), w1 = __int_as_float(e1.y);
        float w2 = __int_as_float(e2.y), w3 = __int_as_float(e3.y);
        float w4 = __int_as_float(e4.y), w5 = __int_as_float(e5.y);
        float w6 = __int_as_float(e6.y), w7 = __int_as_float(e7.y);
        a0.x = fmaf(v0.x, w0, a0.x); a0.y = fmaf(v0.y, w0, a0.y);
        a1.x = fmaf(v1.x, w1, a1.x); a1.y = fmaf(v1.y, w1, a1.y);
        a2.x = fmaf(v2.x, w2, a2.x); a2.y = fmaf(v2.y, w2, a2.y);
        a3.x = fmaf(v3.x, w3, a3.x); a3.y = fmaf(v3.y, w3, a3.y);
        a0.x = fmaf(v4.x, w4, a0.x); a0.y = fmaf(v4.y, w4, a0.y);
        a1.x = fmaf(v5.x, w5, a1.x); a1.y = fmaf(v5.y, w5, a1.y);
        a2.x = fmaf(v6.x, w6, a2.x); a2.y = fmaf(v6.y, w6, a2.y);
        a3.x = fmaf(v7.x, w7, a3.x); a3.y = fmaf(v7.y, w7, a3.y);
    }
    for (; j < end; ++j) {
        int2 e = edat[j];
        float w = __int_as_float(e.y);
        float2 v = ((const float2*)(node + (size_t)e.x * HIDDEN))[lane];
        a0.x = fmaf(v.x, w, a0.x); a0.y = fmaf(v.y, w, a0.y);
    }
    float2 base = ((const float2*)(node + (size_t)n * HIDDEN))[lane];
    float sx = base.x + dn * ((a0.x + a1.x) + (a2.x + a3.x));
    float sy = base.y + dn * ((a0.y + a1.y) + (a2.y + a3.y));
    ((float2*)(out + (size_t)n * HIDDEN))[lane] = make_float2(sx, sy);
}

// ---------------- GraphNorm ----------------

__global__ void stats_kernel(const float* __restrict__ h, const int* __restrict__ batch,
                             float* __restrict__ sum, float* __restrict__ sumsq) {
    int sub = threadIdx.x >> 5;
    int c4 = (threadIdx.x & 31) << 2;
    int i0 = blockIdx.x * 64;
    float4 s = make_float4(0.f, 0.f, 0.f, 0.f);
    float4 ss = make_float4(0.f, 0.f, 0.f, 0.f);
    int gcur = -1;
    for (int k = 0; k < 8; ++k) {
        int i = i0 + k * 8 + sub;
        if (i >= N_NODES) break;
        int g = batch[i];
        if (g != gcur) {
            if (gcur >= 0) {
                float* sp = &sum[gcur * HIDDEN + c4];
                atomicAdd(sp + 0, s.x); atomicAdd(sp + 1, s.y);
                atomicAdd(sp + 2, s.z); atomicAdd(sp + 3, s.w);
                float* qp = &sumsq[gcur * HIDDEN + c4];
                atomicAdd(qp + 0, ss.x); atomicAdd(qp + 1, ss.y);
                atomicAdd(qp + 2, ss.z); atomicAdd(qp + 3, ss.w);
            }
            gcur = g;
            s = make_float4(0.f, 0.f, 0.f, 0.f);
            ss = make_float4(0.f, 0.f, 0.f, 0.f);
        }
        float4 v = *(const float4*)(h + (size_t)i * HIDDEN + c4);
        s.x += v.x; s.y += v.y; s.z += v.z; s.w += v.w;
        ss.x += v.x * v.x; ss.y += v.y * v.y; ss.z += v.z * v.z; ss.w += v.w * v.w;
    }
    if (gcur >= 0) {
        float* sp = &sum[gcur * HIDDEN + c4];
        atomicAdd(sp + 0, s.x); atomicAdd(sp + 1, s.y);
        atomicAdd(sp + 2, s.z); atomicAdd(sp + 3, s.w);
        float* qp = &sumsq[gcur * HIDDEN + c4];
        atomicAdd(qp + 0, ss.x); atomicAdd(qp + 1, ss.y);
        atomicAdd(qp + 2, ss.z); atomicAdd(qp + 3, ss.w);
    }
}

__global__ void finalize_kernel(const float* __restrict__ sum, const float* __restrict__ sumsq,
                                const int* __restrict__ batch,
                                const float* __restrict__ mean_scale,
                                const float* __restrict__ weight,
                                float* __restrict__ msc, float* __restrict__ scale) {
    int t = blockIdx.x * blockDim.x + threadIdx.x;
    if (t >= NUM_GRAPHS * HIDDEN) return;
    int g = t >> 7;
    int c = t & 127;
    int lo0 = 0, hi0 = N_NODES;
    while (lo0 < hi0) { int m = (lo0 + hi0) >> 1; if (batch[m] < g) lo0 = m + 1; else hi0 = m; }
    int lo1 = lo0, hi1 = N_NODES;
    while (lo1 < hi1) { int m = (lo1 + hi1) >> 1; if (batch[m] < g + 1) lo1 = m + 1; else hi1 = m; }
    float n = fmaxf((float)(lo1 - lo0), 1.0f);
    float mean = sum[t] / n;
    float m2 = sumsq[t] / n;
    float ms = mean * mean_scale[c];
    float var = m2 - 2.f * ms * mean + ms * ms;
    msc[t] = ms;
    scale[t] = weight[c] / sqrtf(var + EPS);
}

__global__ void norm_kernel(float* __restrict__ out, const int* __restrict__ batch,
                            const float* __restrict__ msc, const float* __restrict__ scale,
                            const float* __restrict__ bias) {
    int t = blockIdx.x * blockDim.x + threadIdx.x;
    if (t >= N_NODES * HIDDEN / 4) return;
    int node_i = t >> 5;
    int c4 = (t & 31) << 2;
    int g = batch[node_i];
    float4 h = ((const float4*)out)[t];
    float4 m = *(const float4*)&msc[g * HIDDEN + c4];
    float4 sc = *(const float4*)&scale[g * HIDDEN + c4];
    float4 b = *(const float4*)&bias[c4];
    float4 o;
    o.x = fmaxf((h.x - m.x) * sc.x + b.x, 0.f);
    o.y = fmaxf((h.y - m.y) * sc.y + b.y, 0.f);
    o.z = fmaxf((h.z - m.z) * sc.z + b.z, 0.f);
    o.w = fmaxf((h.w - m.w) * sc.w + b.w, 0.f);
    ((float4*)out)[t] = o;
}

// ---------------- fallback (atomic scatter, small ws) ----------------

__global__ void deg_kernel(const int* __restrict__ col, const float* __restrict__ ea,
                           float* __restrict__ deg) {
    int e = blockIdx.x * blockDim.x + threadIdx.x;
    if (e < N_EDGES) atomicAdd(&deg[col[e]], ea[e]);
}

__global__ void dinv_kernel(float* __restrict__ deg) {
    int i = blockIdx.x * blockDim.x + threadIdx.x;
    if (i < N_NODES) {
        float d = deg[i];
        deg[i] = (d > 0.f) ? (1.0f / sqrtf(d)) : 0.f;
    }
}

__global__ void scatter_kernel(const int* __restrict__ row, const int* __restrict__ col,
                               const float* __restrict__ ea, const float* __restrict__ dinv,
                               const float* __restrict__ node, float* __restrict__ out) {
    int idx = blockIdx.x * blockDim.x + threadIdx.x;
    int e = idx >> 6;
    int lane = idx & 63;
    if (e >= N_EDGES) return;
    int r = row[e];
    int c = col[e];
    float w = dinv[r] * ea[e] * dinv[c];
    const float* src = node + (size_t)r * HIDDEN;
    float* dst = out + (size_t)c * HIDDEN;
    atomicAdd(&dst[lane], src[lane] * w);
    atomicAdd(&dst[lane + 64], src[lane + 64] * w);
}

// ---------------- launch ----------------

extern "C" void kernel_launch(void* const* d_in, const int* in_sizes, int n_in,
                              void* d_out, int out_size, void* d_ws, size_t ws_size,
                              hipStream_t stream) {
    const float* node       = (const float*)d_in[0];
    const int*   eidx       = (const int*)d_in[1];   // [2, E] flat
    const float* ea         = (const float*)d_in[2];
    const int*   batch      = (const int*)d_in[3];
    const float* weight     = (const float*)d_in[4];
    const float* bias       = (const float*)d_in[5];
    const float* mean_scale = (const float*)d_in[6];
    float* out = (float*)d_out;

    const int* row = eidx;
    const int* col = eidx + N_EDGES;

    // ws layout: zeroed prefix [cnt64 u64*50048][sum f*6400][sumsq f*6400]
    char* wsb = (char*)d_ws;
    unsigned long long* cnt64 = (unsigned long long*)wsb;
    float* sum    = (float*)(cnt64 + 50048);
    float* sumsq  = sum + 6400;
    float* dinv   = sumsq + 6400;
    int*   rank   = (int*)(dinv + 50048);
    int*   rowptr = rank + N_EDGES;
    int2*  edat   = (int2*)(rowptr + 50048);
    float* msc    = (float*)(edat + N_EDGES);
    float* scale  = msc + 6400;
    int*   bsum   = (int*)(scale + 6400);
    int*   boff   = bsum + 256;
    size_t need = (size_t)((char*)(boff + 256) - wsb);

    if (ws_size >= need) {
        hipMemsetAsync(d_ws, 0, 50048 * 8 + 6400 * 2 * 4, stream);

        hist_kernel<<<(N_EDGES + 255) / 256, 256, 0, stream>>>(col, ea, cnt64, rank);
        scan1_kernel<<<NBLK, 256, 0, stream>>>(cnt64, bsum, dinv);
        scan2_kernel<<<1, 256, 0, stream>>>(bsum, boff);
        scan3_kernel<<<NBLK, 256, 0, stream>>>(cnt64, boff, rowptr);
        place_kernel<<<(N_EDGES + 255) / 256, 256, 0, stream>>>(
            row, col, ea, (const float*)rank, rowptr, dinv, edat);
        gather_kernel<<<(N_NODES + 3) / 4, 256, 0, stream>>>(
            rowptr, cnt64, edat, dinv, node, out);
    } else {
        // fallback: atomic scatter path
        float* f_deg   = (float*)wsb;
        float* f_sum   = f_deg + 50048;
        float* f_sumsq = f_sum + 6400;
        float* f_msc   = f_sumsq + 6400;
        float* f_scale = f_msc + 6400;
        sum = f_sum; sumsq = f_sumsq; msc = f_msc; scale = f_scale;

        hipMemsetAsync(d_ws, 0, (50048 + 6400 * 2) * sizeof(float), stream);
        hipMemcpyAsync(d_out, node, (size_t)N_NODES * HIDDEN * sizeof(float),
                       hipMemcpyDeviceToDevice, stream);
        deg_kernel<<<(N_EDGES + 255) / 256, 256, 0, stream>>>(col, ea, f_deg);
        dinv_kernel<<<(N_NODES + 255) / 256, 256, 0, stream>>>(f_deg);
        long long st = (long long)N_EDGES * 64;
        scatter_kernel<<<(int)((st + 255) / 256), 256, 0, stream>>>(row, col, ea, f_deg, node, out);
    }

    stats_kernel<<<(N_NODES + 63) / 64, 256, 0, stream>>>(out, batch, sum, sumsq);
    finalize_kernel<<<(NUM_GRAPHS * HIDDEN + 255) / 256, 256, 0, stream>>>(
        sum, sumsq, batch, mean_scale, weight, msc, scale);
    norm_kernel<<<(N_NODES * HIDDEN / 4 + 255) / 256, 256, 0, stream>>>(
        out, batch, msc, scale, bias);
}

// Round 7
// 240.503 us; speedup vs baseline: 3.0148x; 1.0631x over previous
//
#include <hip/hip_runtime.h>

#define N_NODES 50000
#define N_EDGES 640000
#define HIDDEN 128
#define NUM_GRAPHS 50
#define EPS 1e-5f
#define NBLK 196  // ceil(N_NODES/256)

#define CNT_SHIFT 44
#define FIX_MASK ((1ULL << CNT_SHIFT) - 1)
#define FIX_SCALE 4294967296.0f   // 2^32
#define FIX_INV (1.0f / 4294967296.0f)
#define PAD8(c) (((c) + 7) & ~7)
#define EDAT_SLOTS 990208  // >= sum(pad8(cnt)) worst case 990000

__device__ __forceinline__ unsigned int bf16_rne(float f) {
    unsigned int u = __float_as_uint(f);
    return (u + 0x7FFFu + ((u >> 16) & 1u)) >> 16;
}

// ---------------- CSR build ----------------

// ONE packed u64 atomic per edge: [63:44]=count, [43:0]=fixed-point sum(ea).
// Return value's count field = this edge's CSR slot rank.
__global__ void hist_kernel(const int* __restrict__ col, const float* __restrict__ ea,
                            unsigned long long* __restrict__ cnt64, int* __restrict__ rank) {
    int e = blockIdx.x * blockDim.x + threadIdx.x;
    if (e >= N_EDGES) return;
    int c = col[e];
    unsigned long long fx = (unsigned long long)(ea[e] * FIX_SCALE + 0.5f);
    unsigned long long old = atomicAdd(&cnt64[c], (1ULL << CNT_SHIFT) | fx);
    rank[e] = (int)(old >> CNT_SHIFT);
}

// unpack cnt64 -> dinv; per-256-block sums of PADDED counts
__global__ void scan1_kernel(const unsigned long long* __restrict__ cnt64,
                             int* __restrict__ bsum, float* __restrict__ dinv) {
    __shared__ int lds[256];
    int i = blockIdx.x * 256 + threadIdx.x;
    int pc = 0;
    if (i < N_NODES) {
        unsigned long long v = cnt64[i];
        int c = (int)(v >> CNT_SHIFT);
        pc = PAD8(c);
        unsigned long long lo = v & FIX_MASK;
        float deg = (float)lo * FIX_INV;
        dinv[i] = (lo != 0ULL) ? (1.0f / sqrtf(deg)) : 0.f;
    }
    lds[threadIdx.x] = pc;
    __syncthreads();
    for (int off = 128; off > 0; off >>= 1) {
        if (threadIdx.x < off) lds[threadIdx.x] += lds[threadIdx.x + off];
        __syncthreads();
    }
    if (threadIdx.x == 0) bsum[blockIdx.x] = lds[0];
}

// rowptr over padded counts; inline exclusive prefix of bsum (196 entries)
__global__ void scan3_kernel(const unsigned long long* __restrict__ cnt64,
                             const int* __restrict__ bsum, int* __restrict__ rowptr) {
    __shared__ int lds[256];
    __shared__ int base_s;
    int t = threadIdx.x;
    int b = (t < (int)blockIdx.x && t < NBLK) ? bsum[t] : 0;
    lds[t] = b;
    __syncthreads();
    for (int off = 128; off > 0; off >>= 1) {
        if (t < off) lds[t] += lds[t + off];
        __syncthreads();
    }
    if (t == 0) base_s = lds[0];
    __syncthreads();
    int base = base_s;
    __syncthreads();
    int i = blockIdx.x * 256 + t;
    int v = (i < N_NODES) ? PAD8((int)(cnt64[i] >> CNT_SHIFT)) : 0;
    lds[t] = v;
    __syncthreads();
    for (int off = 1; off < 256; off <<= 1) {
        int x = (t >= off) ? lds[t - off] : 0;
        __syncthreads();
        lds[t] += x;
        __syncthreads();
    }
    if (i < N_NODES) rowptr[i] = base + lds[t] - v;  // exclusive, padded
}

// scaled bf16 node rows: snode[n][c/2] = pack(bf16(node*dinv[n]))
__global__ void convert_kernel(const float* __restrict__ node, const float* __restrict__ dinv,
                               unsigned int* __restrict__ snode) {
    int t = blockIdx.x * blockDim.x + threadIdx.x;  // one u32 (2 ch) per thread
    if (t >= N_NODES * 64) return;
    int n = t >> 6;
    float d = dinv[n];
    float2 v = ((const float2*)node)[t];
    unsigned int lo = bf16_rne(v.x * d);
    unsigned int hi = bf16_rne(v.y * d);
    snode[t] = lo | (hi << 16);
}

// atomic-free placement: slot = rowptr[col] + rank[e]; store (src, ea)
__global__ void place_kernel(const int* __restrict__ row, const int* __restrict__ col,
                             const float* __restrict__ ea, const int* __restrict__ rank,
                             const int* __restrict__ rowptr, int2* __restrict__ edat) {
    int e = blockIdx.x * blockDim.x + threadIdx.x;
    if (e >= N_EDGES) return;
    int r = row[e], c = col[e];
    int pos = rowptr[c] + rank[e];
    edat[pos] = make_int2(r, __float_as_int(ea[e]));
}

// one wave per target node; lane = 2 channels (bf16x2); padded 8-deep pipeline
__global__ void gather_kernel(const int* __restrict__ rowptr,
                              const unsigned long long* __restrict__ cnt64,
                              const int2* __restrict__ edat, const float* __restrict__ dinv,
                              const unsigned int* __restrict__ snode,
                              const float* __restrict__ node, float* __restrict__ out) {
    int n = blockIdx.x * 4 + (threadIdx.x >> 6);
    int lane = threadIdx.x & 63;
    if (n >= N_NODES) return;
    int cnt = (int)(cnt64[n] >> CNT_SHIFT);
    int iters = (cnt + 7) >> 3;
    int j = rowptr[n];
    float dn = dinv[n];
    float2 a0 = {0.f, 0.f}, a1 = {0.f, 0.f}, a2 = {0.f, 0.f}, a3 = {0.f, 0.f};
    for (int it = 0; it < iters; ++it, j += 8) {
        int2 e0 = edat[j + 0]; int2 e1 = edat[j + 1];
        int2 e2 = edat[j + 2]; int2 e3 = edat[j + 3];
        int2 e4 = edat[j + 4]; int2 e5 = edat[j + 5];
        int2 e6 = edat[j + 6]; int2 e7 = edat[j + 7];
        unsigned int p0 = snode[(size_t)e0.x * 64 + lane];
        unsigned int p1 = snode[(size_t)e1.x * 64 + lane];
        unsigned int p2 = snode[(size_t)e2.x * 64 + lane];
        unsigned int p3 = snode[(size_t)e3.x * 64 + lane];
        unsigned int p4 = snode[(size_t)e4.x * 64 + lane];
        unsigned int p5 = snode[(size_t)e5.x * 64 + lane];
        unsigned int p6 = snode[(size_t)e6.x * 64 + lane];
        unsigned int p7 = snode[(size_t)e7.x * 64 + lane];
        float w0 = __int_as_float(e0.y), w1 = __int_as_float(e1.y);
        float w2 = __int_as_float(e2.y), w3 = __int_as_float(e3.y);
        float w4 = __int_as_float(e4.y), w5 = __int_as_float(e5.y);
        float w6 = __int_as_float(e6.y), w7 = __int_as_float(e7.y);
        a0.x = fmaf(__uint_as_float(p0 << 16), w0, a0.x);
        a0.y = fmaf(__uint_as_float(p0 & 0xFFFF0000u), w0, a0.y);
        a1.x = fmaf(__uint_as_float(p1 << 16), w1, a1.x);
        a1.y = fmaf(__uint_as_float(p1 & 0xFFFF0000u), w1, a1.y);
        a2.x = fmaf(__uint_as_float(p2 << 16), w2, a2.x);
        a2.y = fmaf(__uint_as_float(p2 & 0xFFFF0000u), w2, a2.y);
        a3.x = fmaf(__uint_as_float(p3 << 16), w3, a3.x);
        a3.y = fmaf(__uint_as_float(p3 & 0xFFFF0000u), w3, a3.y);
        a0.x = fmaf(__uint_as_float(p4 << 16), w4, a0.x);
        a0.y = fmaf(__uint_as_float(p4 & 0xFFFF0000u), w4, a0.y);
        a1.x = fmaf(__uint_as_float(p5 << 16), w5, a1.x);
        a1.y = fmaf(__uint_as_float(p5 & 0xFFFF0000u), w5, a1.y);
        a2.x = fmaf(__uint_as_float(p6 << 16), w6, a2.x);
        a2.y = fmaf(__uint_as_float(p6 & 0xFFFF0000u), w6, a2.y);
        a3.x = fmaf(__uint_as_float(p7 << 16), w7, a3.x);
        a3.y = fmaf(__uint_as_float(p7 & 0xFFFF0000u), w7, a3.y);
    }
    float2 base = ((const float2*)(node + (size_t)n * HIDDEN))[lane];
    float sx = base.x + dn * ((a0.x + a1.x) + (a2.x + a3.x));
    float sy = base.y + dn * ((a0.y + a1.y) + (a2.y + a3.y));
    ((float2*)(out + (size_t)n * HIDDEN))[lane] = make_float2(sx, sy);
}

// ---------------- GraphNorm ----------------

__global__ void stats_kernel(const float* __restrict__ h, const int* __restrict__ batch,
                             float* __restrict__ sum, float* __restrict__ sumsq) {
    int sub = threadIdx.x >> 5;
    int c4 = (threadIdx.x & 31) << 2;
    int i0 = blockIdx.x * 64;
    float4 s = make_float4(0.f, 0.f, 0.f, 0.f);
    float4 ss = make_float4(0.f, 0.f, 0.f, 0.f);
    int gcur = -1;
    for (int k = 0; k < 8; ++k) {
        int i = i0 + k * 8 + sub;
        if (i >= N_NODES) break;
        int g = batch[i];
        if (g != gcur) {
            if (gcur >= 0) {
                float* sp = &sum[gcur * HIDDEN + c4];
                atomicAdd(sp + 0, s.x); atomicAdd(sp + 1, s.y);
                atomicAdd(sp + 2, s.z); atomicAdd(sp + 3, s.w);
                float* qp = &sumsq[gcur * HIDDEN + c4];
                atomicAdd(qp + 0, ss.x); atomicAdd(qp + 1, ss.y);
                atomicAdd(qp + 2, ss.z); atomicAdd(qp + 3, ss.w);
            }
            gcur = g;
            s = make_float4(0.f, 0.f, 0.f, 0.f);
            ss = make_float4(0.f, 0.f, 0.f, 0.f);
        }
        float4 v = *(const float4*)(h + (size_t)i * HIDDEN + c4);
        s.x += v.x; s.y += v.y; s.z += v.z; s.w += v.w;
        ss.x += v.x * v.x; ss.y += v.y * v.y; ss.z += v.z * v.z; ss.w += v.w * v.w;
    }
    if (gcur >= 0) {
        float* sp = &sum[gcur * HIDDEN + c4];
        atomicAdd(sp + 0, s.x); atomicAdd(sp + 1, s.y);
        atomicAdd(sp + 2, s.z); atomicAdd(sp + 3, s.w);
        float* qp = &sumsq[gcur * HIDDEN + c4];
        atomicAdd(qp + 0, ss.x); atomicAdd(qp + 1, ss.y);
        atomicAdd(qp + 2, ss.z); atomicAdd(qp + 3, ss.w);
    }
}

__global__ void finalize_kernel(const float* __restrict__ sum, const float* __restrict__ sumsq,
                                const int* __restrict__ batch,
                                const float* __restrict__ mean_scale,
                                const float* __restrict__ weight,
                                float* __restrict__ msc, float* __restrict__ scale) {
    int t = blockIdx.x * blockDim.x + threadIdx.x;
    if (t >= NUM_GRAPHS * HIDDEN) return;
    int g = t >> 7;
    int c = t & 127;
    int lo0 = 0, hi0 = N_NODES;
    while (lo0 < hi0) { int m = (lo0 + hi0) >> 1; if (batch[m] < g) lo0 = m + 1; else hi0 = m; }
    int lo1 = lo0, hi1 = N_NODES;
    while (lo1 < hi1) { int m = (lo1 + hi1) >> 1; if (batch[m] < g + 1) lo1 = m + 1; else hi1 = m; }
    float n = fmaxf((float)(lo1 - lo0), 1.0f);
    float mean = sum[t] / n;
    float m2 = sumsq[t] / n;
    float ms = mean * mean_scale[c];
    float var = m2 - 2.f * ms * mean + ms * ms;
    msc[t] = ms;
    scale[t] = weight[c] / sqrtf(var + EPS);
}

__global__ void norm_kernel(float* __restrict__ out, const int* __restrict__ batch,
                            const float* __restrict__ msc, const float* __restrict__ scale,
                            const float* __restrict__ bias) {
    int t = blockIdx.x * blockDim.x + threadIdx.x;
    if (t >= N_NODES * HIDDEN / 4) return;
    int node_i = t >> 5;
    int c4 = (t & 31) << 2;
    int g = batch[node_i];
    float4 h = ((const float4*)out)[t];
    float4 m = *(const float4*)&msc[g * HIDDEN + c4];
    float4 sc = *(const float4*)&scale[g * HIDDEN + c4];
    float4 b = *(const float4*)&bias[c4];
    float4 o;
    o.x = fmaxf((h.x - m.x) * sc.x + b.x, 0.f);
    o.y = fmaxf((h.y - m.y) * sc.y + b.y, 0.f);
    o.z = fmaxf((h.z - m.z) * sc.z + b.z, 0.f);
    o.w = fmaxf((h.w - m.w) * sc.w + b.w, 0.f);
    ((float4*)out)[t] = o;
}

// ---------------- fallback (atomic scatter, small ws) ----------------

__global__ void deg_kernel(const int* __restrict__ col, const float* __restrict__ ea,
                           float* __restrict__ deg) {
    int e = blockIdx.x * blockDim.x + threadIdx.x;
    if (e < N_EDGES) atomicAdd(&deg[col[e]], ea[e]);
}

__global__ void dinv_kernel(float* __restrict__ deg) {
    int i = blockIdx.x * blockDim.x + threadIdx.x;
    if (i < N_NODES) {
        float d = deg[i];
        deg[i] = (d > 0.f) ? (1.0f / sqrtf(d)) : 0.f;
    }
}

__global__ void scatter_kernel(const int* __restrict__ row, const int* __restrict__ col,
                               const float* __restrict__ ea, const float* __restrict__ dinv,
                               const float* __restrict__ node, float* __restrict__ out) {
    int idx = blockIdx.x * blockDim.x + threadIdx.x;
    int e = idx >> 6;
    int lane = idx & 63;
    if (e >= N_EDGES) return;
    int r = row[e];
    int c = col[e];
    float w = dinv[r] * ea[e] * dinv[c];
    const float* src = node + (size_t)r * HIDDEN;
    float* dst = out + (size_t)c * HIDDEN;
    atomicAdd(&dst[lane], src[lane] * w);
    atomicAdd(&dst[lane + 64], src[lane + 64] * w);
}

// ---------------- launch ----------------

extern "C" void kernel_launch(void* const* d_in, const int* in_sizes, int n_in,
                              void* d_out, int out_size, void* d_ws, size_t ws_size,
                              hipStream_t stream) {
    const float* node       = (const float*)d_in[0];
    const int*   eidx       = (const int*)d_in[1];   // [2, E] flat
    const float* ea         = (const float*)d_in[2];
    const int*   batch      = (const int*)d_in[3];
    const float* weight     = (const float*)d_in[4];
    const float* bias       = (const float*)d_in[5];
    const float* mean_scale = (const float*)d_in[6];
    float* out = (float*)d_out;

    const int* row = eidx;
    const int* col = eidx + N_EDGES;

    // ws layout: zeroed prefix [cnt64 u64*50048][sum 6400][sumsq 6400][edat int2*EDAT_SLOTS]
    char* wsb = (char*)d_ws;
    unsigned long long* cnt64 = (unsigned long long*)wsb;
    float* sum    = (float*)(cnt64 + 50048);
    float* sumsq  = sum + 6400;
    int2*  edat   = (int2*)(sumsq + 6400);
    float* dinv   = (float*)(edat + EDAT_SLOTS);
    int*   rank   = (int*)(dinv + 50048);
    int*   rowptr = rank + N_EDGES;
    unsigned int* snode = (unsigned int*)(rowptr + 50048);   // 50000*64 u32
    float* msc    = (float*)(snode + 3200000);
    float* scale  = msc + 6400;
    int*   bsum   = (int*)(scale + 6400);
    size_t need = (size_t)((char*)(bsum + 256) - wsb);
    size_t zero_bytes = 50048 * 8 + 6400 * 2 * 4 + (size_t)EDAT_SLOTS * 8;

    if (ws_size >= need) {
        hipMemsetAsync(d_ws, 0, zero_bytes, stream);

        hist_kernel<<<(N_EDGES + 255) / 256, 256, 0, stream>>>(col, ea, cnt64, rank);
        scan1_kernel<<<NBLK, 256, 0, stream>>>(cnt64, bsum, dinv);
        scan3_kernel<<<NBLK, 256, 0, stream>>>(cnt64, bsum, rowptr);
        convert_kernel<<<(N_NODES * 64 + 255) / 256, 256, 0, stream>>>(node, dinv, snode);
        place_kernel<<<(N_EDGES + 255) / 256, 256, 0, stream>>>(row, col, ea, rank, rowptr, edat);
        gather_kernel<<<(N_NODES + 3) / 4, 256, 0, stream>>>(
            rowptr, cnt64, edat, dinv, snode, node, out);
    } else {
        // fallback: atomic scatter path
        float* f_deg   = (float*)wsb;
        float* f_sum   = f_deg + 50048;
        float* f_sumsq = f_sum + 6400;
        float* f_msc   = f_sumsq + 6400;
        float* f_scale = f_msc + 6400;
        sum = f_sum; sumsq = f_sumsq; msc = f_msc; scale = f_scale;

        hipMemsetAsync(d_ws, 0, (50048 + 6400 * 2) * sizeof(float), stream);
        hipMemcpyAsync(d_out, node, (size_t)N_NODES * HIDDEN * sizeof(float),
                       hipMemcpyDeviceToDevice, stream);
        deg_kernel<<<(N_EDGES + 255) / 256, 256, 0, stream>>>(col, ea, f_deg);
        dinv_kernel<<<(N_NODES + 255) / 256, 256, 0, stream>>>(f_deg);
        long long st = (long long)N_EDGES * 64;
        scatter_kernel<<<(int)((st + 255) / 256), 256, 0, stream>>>(row, col, ea, f_deg, node, out);
    }

    stats_kernel<<<(N_NODES + 63) / 64, 256, 0, stream>>>(out, batch, sum, sumsq);
    finalize_kernel<<<(NUM_GRAPHS * HIDDEN + 255) / 256, 256, 0, stream>>>(
        sum, sumsq, batch, mean_scale, weight, msc, scale);
    norm_kernel<<<(N_NODES * HIDDEN / 4 + 255) / 256, 256, 0, stream>>>(
        out, batch, msc, scale, bias);
}

// Round 8
// 207.613 us; speedup vs baseline: 3.4924x; 1.1584x over previous
//
#include <hip/hip_runtime.h>

#define N_NODES 50000
#define N_EDGES 640000
#define HIDDEN 128
#define NUM_GRAPHS 50
#define EPS 1e-5f
#define NBLK 196  // ceil(N_NODES/256)

#define CNT_SHIFT 44
#define FIX_MASK ((1ULL << CNT_SHIFT) - 1)
#define FIX_SCALE 4294967296.0f   // 2^32
#define FIX_INV (1.0f / 4294967296.0f)
#define PAD8(c) (((c) + 7) & ~7)
#define EDAT_SLOTS 990208  // >= sum(pad8(cnt)) worst case 990000

__device__ __forceinline__ unsigned int bf16_rne(float f) {
    unsigned int u = __float_as_uint(f);
    return (u + 0x7FFFu + ((u >> 16) & 1u)) >> 16;
}

// ---------------- CSR build ----------------

// ONE packed u64 atomic per edge: [63:44]=count, [43:0]=fixed-point sum(ea).
// Return value's count field = this edge's CSR slot rank.
__global__ void hist_kernel(const int* __restrict__ col, const float* __restrict__ ea,
                            unsigned long long* __restrict__ cnt64, int* __restrict__ rank) {
    int e = blockIdx.x * blockDim.x + threadIdx.x;
    if (e >= N_EDGES) return;
    int c = col[e];
    unsigned long long fx = (unsigned long long)(ea[e] * FIX_SCALE + 0.5f);
    unsigned long long old = atomicAdd(&cnt64[c], (1ULL << CNT_SHIFT) | fx);
    rank[e] = (int)(old >> CNT_SHIFT);
}

// unpack cnt64 -> dinv; per-256-block sums of PADDED counts
__global__ void scan1_kernel(const unsigned long long* __restrict__ cnt64,
                             int* __restrict__ bsum, float* __restrict__ dinv) {
    __shared__ int lds[256];
    int i = blockIdx.x * 256 + threadIdx.x;
    int pc = 0;
    if (i < N_NODES) {
        unsigned long long v = cnt64[i];
        int c = (int)(v >> CNT_SHIFT);
        pc = PAD8(c);
        unsigned long long lo = v & FIX_MASK;
        float deg = (float)lo * FIX_INV;
        dinv[i] = (lo != 0ULL) ? (1.0f / sqrtf(deg)) : 0.f;
    }
    lds[threadIdx.x] = pc;
    __syncthreads();
    for (int off = 128; off > 0; off >>= 1) {
        if (threadIdx.x < off) lds[threadIdx.x] += lds[threadIdx.x + off];
        __syncthreads();
    }
    if (threadIdx.x == 0) bsum[blockIdx.x] = lds[0];
}

// rowptr over padded counts; inline exclusive prefix of bsum (196 entries)
__global__ void scan3_kernel(const unsigned long long* __restrict__ cnt64,
                             const int* __restrict__ bsum, int* __restrict__ rowptr) {
    __shared__ int lds[256];
    __shared__ int base_s;
    int t = threadIdx.x;
    int b = (t < (int)blockIdx.x && t < NBLK) ? bsum[t] : 0;
    lds[t] = b;
    __syncthreads();
    for (int off = 128; off > 0; off >>= 1) {
        if (t < off) lds[t] += lds[t + off];
        __syncthreads();
    }
    if (t == 0) base_s = lds[0];
    __syncthreads();
    int base = base_s;
    __syncthreads();
    int i = blockIdx.x * 256 + t;
    int v = (i < N_NODES) ? PAD8((int)(cnt64[i] >> CNT_SHIFT)) : 0;
    lds[t] = v;
    __syncthreads();
    for (int off = 1; off < 256; off <<= 1) {
        int x = (t >= off) ? lds[t - off] : 0;
        __syncthreads();
        lds[t] += x;
        __syncthreads();
    }
    if (i < N_NODES) rowptr[i] = base + lds[t] - v;  // exclusive, padded
}

// scaled bf16 node rows: snode[n][c/2] = pack(bf16(node*dinv[n]))
__global__ void convert_kernel(const float* __restrict__ node, const float* __restrict__ dinv,
                               unsigned int* __restrict__ snode) {
    int t = blockIdx.x * blockDim.x + threadIdx.x;  // one u32 (2 ch) per thread
    if (t >= N_NODES * 64) return;
    int n = t >> 6;
    float d = dinv[n];
    float2 v = ((const float2*)node)[t];
    unsigned int lo = bf16_rne(v.x * d);
    unsigned int hi = bf16_rne(v.y * d);
    snode[t] = lo | (hi << 16);
}

// atomic-free placement: slot = rowptr[col] + rank[e]; store (src, ea)
__global__ void place_kernel(const int* __restrict__ row, const int* __restrict__ col,
                             const float* __restrict__ ea, const int* __restrict__ rank,
                             const int* __restrict__ rowptr, int2* __restrict__ edat) {
    int e = blockIdx.x * blockDim.x + threadIdx.x;
    if (e >= N_EDGES) return;
    int r = row[e], c = col[e];
    int pos = rowptr[c] + rank[e];
    edat[pos] = make_int2(r, __float_as_int(ea[e]));
}

// one wave per target node; lane = 2 channels (bf16x2); padded 8-deep pipeline; int4 edge loads
__global__ void gather_kernel(const int* __restrict__ rowptr,
                              const unsigned long long* __restrict__ cnt64,
                              const int2* __restrict__ edat, const float* __restrict__ dinv,
                              const unsigned int* __restrict__ snode,
                              const float* __restrict__ node, float* __restrict__ out) {
    int n = blockIdx.x * 4 + (threadIdx.x >> 6);
    int lane = threadIdx.x & 63;
    if (n >= N_NODES) return;
    int cnt = (int)(cnt64[n] >> CNT_SHIFT);
    int iters = (cnt + 7) >> 3;
    int jj = rowptr[n] >> 1;  // int4 index (rowptr multiple of 8)
    const int4* ed4 = (const int4*)edat;
    float dn = dinv[n];
    float2 a0 = {0.f, 0.f}, a1 = {0.f, 0.f}, a2 = {0.f, 0.f}, a3 = {0.f, 0.f};
    for (int it = 0; it < iters; ++it, jj += 4) {
        int4 q0 = ed4[jj + 0]; int4 q1 = ed4[jj + 1];
        int4 q2 = ed4[jj + 2]; int4 q3 = ed4[jj + 3];
        unsigned int p0 = snode[(size_t)q0.x * 64 + lane];
        unsigned int p1 = snode[(size_t)q0.z * 64 + lane];
        unsigned int p2 = snode[(size_t)q1.x * 64 + lane];
        unsigned int p3 = snode[(size_t)q1.z * 64 + lane];
        unsigned int p4 = snode[(size_t)q2.x * 64 + lane];
        unsigned int p5 = snode[(size_t)q2.z * 64 + lane];
        unsigned int p6 = snode[(size_t)q3.x * 64 + lane];
        unsigned int p7 = snode[(size_t)q3.z * 64 + lane];
        float w0 = __int_as_float(q0.y), w1 = __int_as_float(q0.w);
        float w2 = __int_as_float(q1.y), w3 = __int_as_float(q1.w);
        float w4 = __int_as_float(q2.y), w5 = __int_as_float(q2.w);
        float w6 = __int_as_float(q3.y), w7 = __int_as_float(q3.w);
        a0.x = fmaf(__uint_as_float(p0 << 16), w0, a0.x);
        a0.y = fmaf(__uint_as_float(p0 & 0xFFFF0000u), w0, a0.y);
        a1.x = fmaf(__uint_as_float(p1 << 16), w1, a1.x);
        a1.y = fmaf(__uint_as_float(p1 & 0xFFFF0000u), w1, a1.y);
        a2.x = fmaf(__uint_as_float(p2 << 16), w2, a2.x);
        a2.y = fmaf(__uint_as_float(p2 & 0xFFFF0000u), w2, a2.y);
        a3.x = fmaf(__uint_as_float(p3 << 16), w3, a3.x);
        a3.y = fmaf(__uint_as_float(p3 & 0xFFFF0000u), w3, a3.y);
        a0.x = fmaf(__uint_as_float(p4 << 16), w4, a0.x);
        a0.y = fmaf(__uint_as_float(p4 & 0xFFFF0000u), w4, a0.y);
        a1.x = fmaf(__uint_as_float(p5 << 16), w5, a1.x);
        a1.y = fmaf(__uint_as_float(p5 & 0xFFFF0000u), w5, a1.y);
        a2.x = fmaf(__uint_as_float(p6 << 16), w6, a2.x);
        a2.y = fmaf(__uint_as_float(p6 & 0xFFFF0000u), w6, a2.y);
        a3.x = fmaf(__uint_as_float(p7 << 16), w7, a3.x);
        a3.y = fmaf(__uint_as_float(p7 & 0xFFFF0000u), w7, a3.y);
    }
    float2 base = ((const float2*)(node + (size_t)n * HIDDEN))[lane];
    float sx = base.x + dn * ((a0.x + a1.x) + (a2.x + a3.x));
    float sy = base.y + dn * ((a0.y + a1.y) + (a2.y + a3.y));
    ((float2*)(out + (size_t)n * HIDDEN))[lane] = make_float2(sx, sy);
}

// ---------------- GraphNorm (atomic-free two-phase) ----------------

// grid = NUM_GRAPHS*8 blocks; block = (g, chunk). Binary-search graph span,
// register-accumulate, LDS-reduce across 8 sub-rows, write one partial row.
__global__ void stats_p1_kernel(const float* __restrict__ h, const int* __restrict__ batch,
                                float* __restrict__ partial) {
    __shared__ float4 lds_s[256];
    __shared__ float4 lds_q[256];
    int g = blockIdx.x >> 3;
    int ck = blockIdx.x & 7;
    int l0 = 0, h0 = N_NODES;
    while (l0 < h0) { int m = (l0 + h0) >> 1; if (batch[m] < g) l0 = m + 1; else h0 = m; }
    int l1 = l0, h1 = N_NODES;
    while (l1 < h1) { int m = (l1 + h1) >> 1; if (batch[m] < g + 1) l1 = m + 1; else h1 = m; }
    int cnt = l1 - l0;
    int len = (cnt + 7) >> 3;
    int i0 = l0 + ck * len;
    int i1 = i0 + len; if (i1 > l1) i1 = l1;
    int sub = threadIdx.x >> 5;
    int c4 = (threadIdx.x & 31) << 2;
    float4 s = make_float4(0.f, 0.f, 0.f, 0.f);
    float4 q = make_float4(0.f, 0.f, 0.f, 0.f);
    for (int i = i0 + sub; i < i1; i += 8) {
        float4 v = *(const float4*)(h + (size_t)i * HIDDEN + c4);
        s.x += v.x; s.y += v.y; s.z += v.z; s.w += v.w;
        q.x += v.x * v.x; q.y += v.y * v.y; q.z += v.z * v.z; q.w += v.w * v.w;
    }
    lds_s[threadIdx.x] = s; lds_q[threadIdx.x] = q;
    __syncthreads();
    for (int off = 128; off >= 32; off >>= 1) {
        if (threadIdx.x < off) {
            float4 a = lds_s[threadIdx.x + off];
            float4 b = lds_q[threadIdx.x + off];
            float4 xs = lds_s[threadIdx.x];
            float4 xq = lds_q[threadIdx.x];
            xs.x += a.x; xs.y += a.y; xs.z += a.z; xs.w += a.w;
            xq.x += b.x; xq.y += b.y; xq.z += b.z; xq.w += b.w;
            lds_s[threadIdx.x] = xs; lds_q[threadIdx.x] = xq;
        }
        __syncthreads();
    }
    if (threadIdx.x < 32) {
        float* dst = partial + (size_t)blockIdx.x * 256;
        *(float4*)(dst + c4) = lds_s[threadIdx.x];
        *(float4*)(dst + 128 + c4) = lds_q[threadIdx.x];
    }
}

// fold 8 partials per (g,c4) + finalize msc/scale; 1600 threads
__global__ void stats_p2_kernel(const float* __restrict__ partial, const int* __restrict__ batch,
                                const float* __restrict__ mean_scale,
                                const float* __restrict__ weight,
                                float* __restrict__ msc, float* __restrict__ scale) {
    int t = blockIdx.x * blockDim.x + threadIdx.x;
    if (t >= NUM_GRAPHS * 32) return;
    int g = t >> 5;
    int c4 = (t & 31) << 2;
    float4 s = make_float4(0.f, 0.f, 0.f, 0.f);
    float4 q = make_float4(0.f, 0.f, 0.f, 0.f);
    for (int ck = 0; ck < 8; ++ck) {
        const float* p = partial + (size_t)(g * 8 + ck) * 256;
        float4 a = *(const float4*)(p + c4);
        float4 b = *(const float4*)(p + 128 + c4);
        s.x += a.x; s.y += a.y; s.z += a.z; s.w += a.w;
        q.x += b.x; q.y += b.y; q.z += b.z; q.w += b.w;
    }
    int l0 = 0, h0 = N_NODES;
    while (l0 < h0) { int m = (l0 + h0) >> 1; if (batch[m] < g) l0 = m + 1; else h0 = m; }
    int l1 = l0, h1 = N_NODES;
    while (l1 < h1) { int m = (l1 + h1) >> 1; if (batch[m] < g + 1) l1 = m + 1; else h1 = m; }
    float n = fmaxf((float)(l1 - l0), 1.0f);
    float4 mm, sc;
    {
        float mean = s.x / n, m2 = q.x / n;
        float ms = mean * mean_scale[c4 + 0];
        mm.x = ms; sc.x = weight[c4 + 0] / sqrtf(m2 - 2.f * ms * mean + ms * ms + EPS);
    }
    {
        float mean = s.y / n, m2 = q.y / n;
        float ms = mean * mean_scale[c4 + 1];
        mm.y = ms; sc.y = weight[c4 + 1] / sqrtf(m2 - 2.f * ms * mean + ms * ms + EPS);
    }
    {
        float mean = s.z / n, m2 = q.z / n;
        float ms = mean * mean_scale[c4 + 2];
        mm.z = ms; sc.z = weight[c4 + 2] / sqrtf(m2 - 2.f * ms * mean + ms * ms + EPS);
    }
    {
        float mean = s.w / n, m2 = q.w / n;
        float ms = mean * mean_scale[c4 + 3];
        mm.w = ms; sc.w = weight[c4 + 3] / sqrtf(m2 - 2.f * ms * mean + ms * ms + EPS);
    }
    *(float4*)&msc[g * HIDDEN + c4] = mm;
    *(float4*)&scale[g * HIDDEN + c4] = sc;
}

__global__ void norm_kernel(float* __restrict__ out, const int* __restrict__ batch,
                            const float* __restrict__ msc, const float* __restrict__ scale,
                            const float* __restrict__ bias) {
    int t = blockIdx.x * blockDim.x + threadIdx.x;
    if (t >= N_NODES * HIDDEN / 4) return;
    int node_i = t >> 5;
    int c4 = (t & 31) << 2;
    int g = batch[node_i];
    float4 h = ((const float4*)out)[t];
    float4 m = *(const float4*)&msc[g * HIDDEN + c4];
    float4 sc = *(const float4*)&scale[g * HIDDEN + c4];
    float4 b = *(const float4*)&bias[c4];
    float4 o;
    o.x = fmaxf((h.x - m.x) * sc.x + b.x, 0.f);
    o.y = fmaxf((h.y - m.y) * sc.y + b.y, 0.f);
    o.z = fmaxf((h.z - m.z) * sc.z + b.z, 0.f);
    o.w = fmaxf((h.w - m.w) * sc.w + b.w, 0.f);
    ((float4*)out)[t] = o;
}

// ---------------- fallback (atomic path, small ws) ----------------

__global__ void deg_kernel(const int* __restrict__ col, const float* __restrict__ ea,
                           float* __restrict__ deg) {
    int e = blockIdx.x * blockDim.x + threadIdx.x;
    if (e < N_EDGES) atomicAdd(&deg[col[e]], ea[e]);
}

__global__ void dinv_kernel(float* __restrict__ deg) {
    int i = blockIdx.x * blockDim.x + threadIdx.x;
    if (i < N_NODES) {
        float d = deg[i];
        deg[i] = (d > 0.f) ? (1.0f / sqrtf(d)) : 0.f;
    }
}

__global__ void scatter_kernel(const int* __restrict__ row, const int* __restrict__ col,
                               const float* __restrict__ ea, const float* __restrict__ dinv,
                               const float* __restrict__ node, float* __restrict__ out) {
    int idx = blockIdx.x * blockDim.x + threadIdx.x;
    int e = idx >> 6;
    int lane = idx & 63;
    if (e >= N_EDGES) return;
    int r = row[e];
    int c = col[e];
    float w = dinv[r] * ea[e] * dinv[c];
    const float* src = node + (size_t)r * HIDDEN;
    float* dst = out + (size_t)c * HIDDEN;
    atomicAdd(&dst[lane], src[lane] * w);
    atomicAdd(&dst[lane + 64], src[lane + 64] * w);
}

__global__ void stats_kernel(const float* __restrict__ h, const int* __restrict__ batch,
                             float* __restrict__ sum, float* __restrict__ sumsq) {
    int sub = threadIdx.x >> 5;
    int c4 = (threadIdx.x & 31) << 2;
    int i0 = blockIdx.x * 64;
    float4 s = make_float4(0.f, 0.f, 0.f, 0.f);
    float4 ss = make_float4(0.f, 0.f, 0.f, 0.f);
    int gcur = -1;
    for (int k = 0; k < 8; ++k) {
        int i = i0 + k * 8 + sub;
        if (i >= N_NODES) break;
        int g = batch[i];
        if (g != gcur) {
            if (gcur >= 0) {
                float* sp = &sum[gcur * HIDDEN + c4];
                atomicAdd(sp + 0, s.x); atomicAdd(sp + 1, s.y);
                atomicAdd(sp + 2, s.z); atomicAdd(sp + 3, s.w);
                float* qp = &sumsq[gcur * HIDDEN + c4];
                atomicAdd(qp + 0, ss.x); atomicAdd(qp + 1, ss.y);
                atomicAdd(qp + 2, ss.z); atomicAdd(qp + 3, ss.w);
            }
            gcur = g;
            s = make_float4(0.f, 0.f, 0.f, 0.f);
            ss = make_float4(0.f, 0.f, 0.f, 0.f);
        }
        float4 v = *(const float4*)(h + (size_t)i * HIDDEN + c4);
        s.x += v.x; s.y += v.y; s.z += v.z; s.w += v.w;
        ss.x += v.x * v.x; ss.y += v.y * v.y; ss.z += v.z * v.z; ss.w += v.w * v.w;
    }
    if (gcur >= 0) {
        float* sp = &sum[gcur * HIDDEN + c4];
        atomicAdd(sp + 0, s.x); atomicAdd(sp + 1, s.y);
        atomicAdd(sp + 2, s.z); atomicAdd(sp + 3, s.w);
        float* qp = &sumsq[gcur * HIDDEN + c4];
        atomicAdd(qp + 0, ss.x); atomicAdd(qp + 1, ss.y);
        atomicAdd(qp + 2, ss.z); atomicAdd(qp + 3, ss.w);
    }
}

__global__ void finalize_kernel(const float* __restrict__ sum, const float* __restrict__ sumsq,
                                const int* __restrict__ batch,
                                const float* __restrict__ mean_scale,
                                const float* __restrict__ weight,
                                float* __restrict__ msc, float* __restrict__ scale) {
    int t = blockIdx.x * blockDim.x + threadIdx.x;
    if (t >= NUM_GRAPHS * HIDDEN) return;
    int g = t >> 7;
    int c = t & 127;
    int lo0 = 0, hi0 = N_NODES;
    while (lo0 < hi0) { int m = (lo0 + hi0) >> 1; if (batch[m] < g) lo0 = m + 1; else hi0 = m; }
    int lo1 = lo0, hi1 = N_NODES;
    while (lo1 < hi1) { int m = (lo1 + hi1) >> 1; if (batch[m] < g + 1) lo1 = m + 1; else hi1 = m; }
    float n = fmaxf((float)(lo1 - lo0), 1.0f);
    float mean = sum[t] / n;
    float m2 = sumsq[t] / n;
    float ms = mean * mean_scale[c];
    float var = m2 - 2.f * ms * mean + ms * ms;
    msc[t] = ms;
    scale[t] = weight[c] / sqrtf(var + EPS);
}

// ---------------- launch ----------------

extern "C" void kernel_launch(void* const* d_in, const int* in_sizes, int n_in,
                              void* d_out, int out_size, void* d_ws, size_t ws_size,
                              hipStream_t stream) {
    const float* node       = (const float*)d_in[0];
    const int*   eidx       = (const int*)d_in[1];   // [2, E] flat
    const float* ea         = (const float*)d_in[2];
    const int*   batch      = (const int*)d_in[3];
    const float* weight     = (const float*)d_in[4];
    const float* bias       = (const float*)d_in[5];
    const float* mean_scale = (const float*)d_in[6];
    float* out = (float*)d_out;

    const int* row = eidx;
    const int* col = eidx + N_EDGES;

    // ws layout: zeroed prefix [cnt64 u64*50048][sum 6400][sumsq 6400][edat int2*EDAT_SLOTS]
    char* wsb = (char*)d_ws;
    unsigned long long* cnt64 = (unsigned long long*)wsb;
    float* sum    = (float*)(cnt64 + 50048);
    float* sumsq  = sum + 6400;
    int2*  edat   = (int2*)(sumsq + 6400);
    float* dinv   = (float*)(edat + EDAT_SLOTS);
    int*   rank   = (int*)(dinv + 50048);
    int*   rowptr = rank + N_EDGES;
    unsigned int* snode = (unsigned int*)(rowptr + 50048);   // 50000*64 u32
    float* msc    = (float*)(snode + 3200000);
    float* scale  = msc + 6400;
    int*   bsum   = (int*)(scale + 6400);
    float* partial = (float*)(bsum + 256);                   // 400*256 floats
    size_t need = (size_t)((char*)(partial + NUM_GRAPHS * 8 * 256) - wsb);
    size_t zero_bytes = 50048 * 8 + 6400 * 2 * 4 + (size_t)EDAT_SLOTS * 8;

    if (ws_size >= need) {
        hipMemsetAsync(d_ws, 0, zero_bytes, stream);

        hist_kernel<<<(N_EDGES + 255) / 256, 256, 0, stream>>>(col, ea, cnt64, rank);
        scan1_kernel<<<NBLK, 256, 0, stream>>>(cnt64, bsum, dinv);
        scan3_kernel<<<NBLK, 256, 0, stream>>>(cnt64, bsum, rowptr);
        convert_kernel<<<(N_NODES * 64 + 255) / 256, 256, 0, stream>>>(node, dinv, snode);
        place_kernel<<<(N_EDGES + 255) / 256, 256, 0, stream>>>(row, col, ea, rank, rowptr, edat);
        gather_kernel<<<(N_NODES + 3) / 4, 256, 0, stream>>>(
            rowptr, cnt64, edat, dinv, snode, node, out);

        stats_p1_kernel<<<NUM_GRAPHS * 8, 256, 0, stream>>>(out, batch, partial);
        stats_p2_kernel<<<(NUM_GRAPHS * 32 + 255) / 256, 256, 0, stream>>>(
            partial, batch, mean_scale, weight, msc, scale);
    } else {
        // fallback: atomic path
        float* f_deg   = (float*)wsb;
        float* f_sum   = f_deg + 50048;
        float* f_sumsq = f_sum + 6400;
        float* f_msc   = f_sumsq + 6400;
        float* f_scale = f_msc + 6400;
        msc = f_msc; scale = f_scale;

        hipMemsetAsync(d_ws, 0, (50048 + 6400 * 2) * sizeof(float), stream);
        hipMemcpyAsync(d_out, node, (size_t)N_NODES * HIDDEN * sizeof(float),
                       hipMemcpyDeviceToDevice, stream);
        deg_kernel<<<(N_EDGES + 255) / 256, 256, 0, stream>>>(col, ea, f_deg);
        dinv_kernel<<<(N_NODES + 255) / 256, 256, 0, stream>>>(f_deg);
        long long st = (long long)N_EDGES * 64;
        scatter_kernel<<<(int)((st + 255) / 256), 256, 0, stream>>>(row, col, ea, f_deg, node, out);
        stats_kernel<<<(N_NODES + 63) / 64, 256, 0, stream>>>(out, batch, f_sum, f_sumsq);
        finalize_kernel<<<(NUM_GRAPHS * HIDDEN + 255) / 256, 256, 0, stream>>>(
            f_sum, f_sumsq, batch, mean_scale, weight, msc, scale);
    }

    norm_kernel<<<(N_NODES * HIDDEN / 4 + 255) / 256, 256, 0, stream>>>(
        out, batch, msc, scale, bias);
}